// Round 8
// baseline (787.815 us; speedup 1.0000x reference)
//
#include <hip/hip_runtime.h>
#include <hip/hip_bf16.h>

#define NN 20000
#define NE 160000
#define HD 64
#define TT 3

typedef unsigned short ushortx8 __attribute__((ext_vector_type(8)));
typedef float f32x4 __attribute__((ext_vector_type(4)));
typedef __bf16 bf16x8 __attribute__((ext_vector_type(8)));

__device__ __forceinline__ unsigned short f2bf(float f) {
  unsigned int x = __float_as_uint(f);
  unsigned int r = (x + 0x7fffu + ((x >> 16) & 1u)) >> 16;  // RNE, finite inputs
  return (unsigned short)r;
}
__device__ __forceinline__ float bf2f(unsigned short u) {
  return __uint_as_float(((unsigned int)u) << 16);
}

// ---------------- fused precompute: init out, zero counts, h_pre, weight prep ----------------
__global__ __launch_bounds__(256) void k_prep(const float* __restrict__ wp,
    const float* __restrict__ vel, float* __restrict__ PO, float* __restrict__ VO,
    int* __restrict__ counts, int* __restrict__ fill,
    const float* __restrict__ youngs, const float* __restrict__ onehot,
    const float* __restrict__ ym, const float* __restrict__ ys,
    const float* __restrict__ w_ne1, const float* __restrict__ b_ne1, float* __restrict__ h_pre,
    const float* __restrict__ w_em1, const float* __restrict__ w_em2,
    const float* __restrict__ w_nm1, const float* __restrict__ w_nm2,
    const float* __restrict__ w_dec1, const float* __restrict__ w_ne2, const float* __restrict__ w_ee2,
    char* __restrict__ w1em, char* __restrict__ w2em, char* __restrict__ wnm1,
    char* __restrict__ wnm2, char* __restrict__ wdec1, char* __restrict__ wne2,
    char* __restrict__ wee2) {
  int idx = blockIdx.x * 256 + threadIdx.x;
  if (idx < NN * 3) { PO[idx] = wp[idx]; VO[idx] = vel[idx]; }
  if (idx < NN) { counts[idx] = 0; fill[idx] = 0; }
  {  // h_pre (all idx < NN*HD; grid == NN*HD/256)
    int n = idx >> 6, j = idx & 63;
    float a = b_ne1[j];
    float yn = (youngs[n] - ym[0]) / ys[0];
    a += yn * w_ne1[3 * HD + j];
#pragma unroll
    for (int k = 0; k < 9; k++) a += onehot[n * 9 + k] * w_ne1[(4 + k) * HD + j];
    h_pre[idx] = a;
  }
  int w = idx;
  if (w < 12288) {
    int j = w / 192, k = w % 192;
    *(unsigned short*)(w1em + j * 384 + ((k * 2) ^ ((j & 7) << 4))) = f2bf(w_em1[k * 64 + j]);
    return;
  }
  w -= 12288;
  if (w < 4096) {
    int j = w >> 6, k = w & 63;
    *(unsigned short*)(w2em + j * 128 + ((k * 2) ^ ((j & 7) << 4))) = f2bf(w_em2[k * 64 + j]);
    return;
  }
  w -= 4096;
  if (w < 8192) {
    int j = w >> 7, k = w & 127;
    *(unsigned short*)(wnm1 + j * 256 + ((k * 2) ^ ((j & 7) << 4))) = f2bf(w_nm1[k * 64 + j]);
    return;
  }
  w -= 8192;
  if (w < 4096) {
    int j = w >> 6, k = w & 63;
    *(unsigned short*)(wnm2 + j * 128 + ((k * 2) ^ ((j & 7) << 4))) = f2bf(w_nm2[k * 64 + j]);
    return;
  }
  w -= 4096;
  if (w < 4096) {
    int j = w >> 6, k = w & 63;
    *(unsigned short*)(wdec1 + j * 128 + ((k * 2) ^ ((j & 7) << 4))) = f2bf(w_dec1[k * 64 + j]);
    return;
  }
  w -= 4096;
  if (w < 4096) {
    int j = w >> 6, k = w & 63;
    *(unsigned short*)(wne2 + j * 128 + ((k * 2) ^ ((j & 7) << 4))) = f2bf(w_ne2[k * 64 + j]);
    return;
  }
  w -= 4096;
  if (w < 4096) {
    int j = w >> 6, k = w & 63;
    *(unsigned short*)(wee2 + j * 128 + ((k * 2) ^ ((j & 7) << 4))) = f2bf(w_ee2[k * 64 + j]);
    return;
  }
}

// ---------------- static edge encoder via MFMA (once) -> pre-swizzled bf16 ----------------
__global__ __launch_bounds__(256) void k_edge_enc_mfma(const float* __restrict__ eattr,
    const float* __restrict__ emean, const float* __restrict__ estd,
    const float* __restrict__ w_ee1, const float* __restrict__ b_ee1,
    const char* __restrict__ wee2sw, const float* __restrict__ b_ee2,
    char* __restrict__ eenc_sw) {
  __shared__ __align__(16) char s_w2[64 * 128];
  __shared__ __align__(16) char s_hid[64 * 128];
  __shared__ float s_w1[4 * 64], s_b1[64], s_b2[64], s_m[4], s_s[4];
  int tid = threadIdx.x, e0b = blockIdx.x * 64;
  for (int c = tid; c < 512; c += 256) ((ushortx8*)s_w2)[c] = ((const ushortx8*)wee2sw)[c];
  if (tid < 256) s_w1[tid] = w_ee1[tid];
  if (tid < 64) { s_b1[tid] = b_ee1[tid]; s_b2[tid] = b_ee2[tid]; }
  if (tid < 4) { s_m[tid] = emean[tid]; s_s[tid] = estd[tid]; }
  __syncthreads();
  int lane = tid & 63, wv = tid >> 6, l15 = lane & 15, lq = lane >> 4, csub = lq * 8;
  int row_l = wv * 16 + l15, rsw = (l15 & 7) << 4;
  int erow = e0b + row_l;
  float4 at = ((const float4*)eattr)[erow];
  float x0 = (at.x - s_m[0]) / s_s[0];
  float x1 = (at.y - s_m[1]) / s_s[1];
  float x2 = (at.z - s_m[2]) / s_s[2];
  float x3 = (at.w - s_m[3]) / s_s[3];
#pragma unroll 4
  for (int i = 0; i < 16; i++) {
    int rl = wv * 16 + i;
    float y0 = __shfl(x0, i), y1 = __shfl(x1, i), y2 = __shfl(x2, i), y3 = __shfl(x3, i);
    float a = s_b1[lane] + y0 * s_w1[lane] + y1 * s_w1[64 + lane] + y2 * s_w1[128 + lane] + y3 * s_w1[192 + lane];
    *(unsigned short*)(s_hid + rl * 128 + ((lane * 2) ^ ((rl & 7) << 4))) = f2bf(fmaxf(a, 0.f));
  }
  f32x4 acc[4];
#pragma unroll
  for (int n = 0; n < 4; n++) {
    float bv = s_b2[n * 16 + l15];
#pragma unroll
    for (int i = 0; i < 4; i++) acc[n][i] = bv;
  }
#pragma unroll
  for (int kk = 0; kk < 2; kk++) {
    ushortx8 au = *(const ushortx8*)(s_hid + row_l * 128 + (((kk * 32 + csub) * 2) ^ rsw));
    bf16x8 av = __builtin_bit_cast(bf16x8, au);
#pragma unroll
    for (int n = 0; n < 4; n++) {
      int j = n * 16 + l15;
      ushortx8 bu = *(const ushortx8*)(s_w2 + j * 128 + (((kk * 32 + csub) * 2) ^ ((j & 7) << 4)));
      acc[n] = __builtin_amdgcn_mfma_f32_16x16x32_bf16(av, __builtin_bit_cast(bf16x8, bu), acc[n], 0, 0, 0);
    }
  }
#pragma unroll
  for (int n = 0; n < 4; n++) {
#pragma unroll
    for (int i = 0; i < 4; i++) {
      int r = wv * 16 + lq * 4 + i, col = n * 16 + l15;
      *(unsigned short*)(s_hid + r * 128 + ((col * 2) ^ ((r & 7) << 4))) = f2bf(acc[n][i]);
    }
  }
  ushortx8 q0 = *(const ushortx8*)(s_hid + row_l * 128 + lq * 32);
  ushortx8 q1 = *(const ushortx8*)(s_hid + row_l * 128 + lq * 32 + 16);
  *(ushortx8*)(eenc_sw + (size_t)erow * 128 + lq * 32) = q0;
  *(ushortx8*)(eenc_sw + (size_t)erow * 128 + lq * 32 + 16) = q1;
}

// ---------------- CSR build ----------------
__global__ __launch_bounds__(256) void k_count(const int* __restrict__ eidx, int* __restrict__ counts) {
  int e = blockIdx.x * 256 + threadIdx.x;
  if (e < NE) atomicAdd(&counts[eidx[NE + e]], 1);
}

#define SCAN_NB ((NN + 255) / 256)
__global__ __launch_bounds__(256) void k_scanA(const int* __restrict__ counts,
    int* __restrict__ row_ptr, int* __restrict__ bsums) {
  __shared__ int tmp[256];
  int tid = threadIdx.x;
  int g = blockIdx.x * 256 + tid;
  int v = (g < NN) ? counts[g] : 0;
  tmp[tid] = v;
  __syncthreads();
#pragma unroll
  for (int off = 1; off < 256; off <<= 1) {
    int t = (tid >= off) ? tmp[tid - off] : 0;
    __syncthreads();
    tmp[tid] += t;
    __syncthreads();
  }
  if (g < NN) row_ptr[g] = tmp[tid] - v;
  if (tid == 255) bsums[blockIdx.x] = tmp[255];
}

__global__ __launch_bounds__(128) void k_scanB(int* __restrict__ bsums) {
  __shared__ int tmp[128];
  int tid = threadIdx.x;
  int v = (tid < SCAN_NB) ? bsums[tid] : 0;
  tmp[tid] = v;
  __syncthreads();
#pragma unroll
  for (int off = 1; off < 128; off <<= 1) {
    int t = (tid >= off) ? tmp[tid - off] : 0;
    __syncthreads();
    tmp[tid] += t;
    __syncthreads();
  }
  if (tid < SCAN_NB) bsums[tid] = tmp[tid] - v;
}

__global__ __launch_bounds__(256) void k_scanC(int* __restrict__ row_ptr, const int* __restrict__ bsums) {
  int g = blockIdx.x * 256 + threadIdx.x;
  if (g < NN) row_ptr[g] += bsums[blockIdx.x];
  if (g == 0) row_ptr[NN] = NE;
}

__global__ __launch_bounds__(256) void k_place(const int* __restrict__ eidx,
    const int* __restrict__ row_ptr, int* __restrict__ fill, int* __restrict__ slot) {
  int e = blockIdx.x * 256 + threadIdx.x;
  if (e >= NE) return;
  int d = eidx[NE + e];
  int f = atomicAdd(&fill[d], 1);
  slot[e] = row_ptr[d] + f;
}

// ---------------- initial node encoder (t=0 only) ----------------
__global__ __launch_bounds__(256) void k_enc_mfma(const float* __restrict__ vel,
    const float* __restrict__ vmean, const float* __restrict__ vstd,
    const float* __restrict__ w_ne1, const float* __restrict__ h_pre,
    const char* __restrict__ wne2sw, const float* __restrict__ b_ne2,
    float* __restrict__ h, unsigned short* __restrict__ h_bf) {
  __shared__ __align__(16) char s_w2[64 * 128];
  __shared__ __align__(16) char s_hid[64 * 128];
  __shared__ float s_w1[3 * 64], s_b2[64], s_vm[3], s_vs[3];
  int tid = threadIdx.x, n0b = blockIdx.x * 64;
  for (int c = tid; c < 512; c += 256) ((ushortx8*)s_w2)[c] = ((const ushortx8*)wne2sw)[c];
  if (tid < 192) s_w1[tid] = w_ne1[tid];
  if (tid < 64) s_b2[tid] = b_ne2[tid];
  if (tid < 3) { s_vm[tid] = vmean[tid]; s_vs[tid] = vstd[tid]; }
  __syncthreads();
  int lane = tid & 63, wv = tid >> 6, l15 = lane & 15, lq = lane >> 4, csub = lq * 8;
#pragma unroll 4
  for (int i = 0; i < 16; i++) {
    int rl = wv * 16 + i, node = n0b + rl;
    float hv = 0.f;
    if (node < NN) {
      float v0 = (vel[node * 3 + 0] - s_vm[0]) / s_vs[0];
      float v1 = (vel[node * 3 + 1] - s_vm[1]) / s_vs[1];
      float v2 = (vel[node * 3 + 2] - s_vm[2]) / s_vs[2];
      float a = h_pre[(size_t)node * 64 + lane] + v0 * s_w1[lane] + v1 * s_w1[64 + lane] + v2 * s_w1[128 + lane];
      hv = fmaxf(a, 0.f);
    }
    *(unsigned short*)(s_hid + rl * 128 + ((lane * 2) ^ ((rl & 7) << 4))) = f2bf(hv);
  }
  int row_l = wv * 16 + l15, rsw = (l15 & 7) << 4;
  f32x4 acc[4];
#pragma unroll
  for (int n = 0; n < 4; n++) {
    float bv = s_b2[n * 16 + l15];
#pragma unroll
    for (int i = 0; i < 4; i++) acc[n][i] = bv;
  }
#pragma unroll
  for (int kk = 0; kk < 2; kk++) {
    ushortx8 au = *(const ushortx8*)(s_hid + row_l * 128 + (((kk * 32 + csub) * 2) ^ rsw));
    bf16x8 av = __builtin_bit_cast(bf16x8, au);
#pragma unroll
    for (int n = 0; n < 4; n++) {
      int j = n * 16 + l15;
      ushortx8 bu = *(const ushortx8*)(s_w2 + j * 128 + (((kk * 32 + csub) * 2) ^ ((j & 7) << 4)));
      acc[n] = __builtin_amdgcn_mfma_f32_16x16x32_bf16(av, __builtin_bit_cast(bf16x8, bu), acc[n], 0, 0, 0);
    }
  }
#pragma unroll
  for (int n = 0; n < 4; n++) {
#pragma unroll
    for (int i = 0; i < 4; i++) {
      int r = wv * 16 + lq * 4 + i, rowg = n0b + r, col = n * 16 + l15;
      if (rowg < NN) h[(size_t)rowg * 64 + col] = acc[n][i];
      *(unsigned short*)(s_hid + r * 128 + ((col * 2) ^ ((r & 7) << 4))) = f2bf(acc[n][i]);
    }
  }
  int noderow = n0b + row_l;
  if (noderow < NN) {
    ushortx8 q0 = *(const ushortx8*)(s_hid + row_l * 128 + ((lq * 32) ^ rsw));
    ushortx8 q1 = *(const ushortx8*)(s_hid + row_l * 128 + ((lq * 32 + 16) ^ rsw));
    ushortx8* op = (ushortx8*)(h_bf + (size_t)noderow * 64);
    op[lq * 2] = q0;
    op[lq * 2 + 1] = q1;
  }
}

// ---------------- per-deriv: edge MLP via MFMA, persistent, WAVE-PRIVATE staging ----------------
// Each wave owns a 2KB LDS quarter and stages its own 16 contiguous eenc rows
// (coalesced 32B/lane). No block barriers in the tile loop -> waves fully decoupled.
#define EDGE_GRID 1024
__global__ __launch_bounds__(256, 4) void k_edge_mfma(
    const int* __restrict__ eidx, const int* __restrict__ slot,
    const unsigned short* __restrict__ h_bf, const char* __restrict__ eenc_sw,
    const char* __restrict__ w1sw, const char* __restrict__ w2sw,
    const float* __restrict__ b_em1, const float* __restrict__ b_em2,
    unsigned short* __restrict__ emsg) {
  __shared__ __align__(16) char s_w1[64 * 384];    // 24KB
  __shared__ __align__(16) char s_w2[64 * 128];    // 8KB
  __shared__ __align__(16) char s_eh[4 * 16 * 128];  // 8KB, per-wave quarters
  int tid = threadIdx.x;
  int lane = tid & 63, wv = tid >> 6, l15 = lane & 15, lq = lane >> 4, csub = lq * 8;
  int rsw = (l15 & 7) << 4;
  for (int c = tid; c < 1536; c += 256) ((ushortx8*)s_w1)[c] = ((const ushortx8*)w1sw)[c];
  for (int c = tid; c < 512; c += 256) ((ushortx8*)s_w2)[c] = ((const ushortx8*)w2sw)[c];
  float bv1[4], bv2[4];
#pragma unroll
  for (int n = 0; n < 4; n++) { bv1[n] = b_em1[n * 16 + l15]; bv2[n] = b_em2[n * 16 + l15]; }
  char* my_eh = s_eh + wv * 2048;
  __syncthreads();  // weights visible; no block barriers after this

  const int NT = NE / 64;
  ushortx8 stg0, stg1;
  {
    const ushortx8* src = (const ushortx8*)(eenc_sw + ((size_t)blockIdx.x * 64 + wv * 16) * 128);
    stg0 = src[lane * 2];
    stg1 = src[lane * 2 + 1];
  }
  for (int t = blockIdx.x; t < NT; t += EDGE_GRID) {
    int e0b = t * 64;
    int eg = e0b + wv * 16 + l15;
    int sidx = eidx[eg], didx = eidx[NE + eg], sl = slot[eg];
    // write this tile's eenc rows into wave-private LDS (linear copy keeps swizzle:
    // global row swizzle key is e&7 == local row &7 since e0b+wv*16 == 0 mod 8)
    ((ushortx8*)my_eh)[lane * 2] = stg0;
    ((ushortx8*)my_eh)[lane * 2 + 1] = stg1;
    int tn = t + EDGE_GRID;
    if (tn < NT) {  // prefetch next tile under this tile's compute
      const ushortx8* srcn = (const ushortx8*)(eenc_sw + ((size_t)tn * 64 + wv * 16) * 128);
      stg0 = srcn[lane * 2];
      stg1 = srcn[lane * 2 + 1];
    }
    const ushortx8* hs = (const ushortx8*)(h_bf + (size_t)sidx * HD);
    const ushortx8* hd = (const ushortx8*)(h_bf + (size_t)didx * HD);
    ushortx8 a2 = hs[lq];
    ushortx8 a3 = hs[4 + lq];
    ushortx8 a4 = hd[lq];
    ushortx8 a5 = hd[4 + lq];
    ushortx8 a0 = *(const ushortx8*)(my_eh + l15 * 128 + ((csub * 2) ^ rsw));
    ushortx8 a1 = *(const ushortx8*)(my_eh + l15 * 128 + ((64 + csub * 2) ^ rsw));
    f32x4 acc[4];
#pragma unroll
    for (int n = 0; n < 4; n++) {
#pragma unroll
      for (int i = 0; i < 4; i++) acc[n][i] = bv1[n];
    }
    ushortx8 af[6] = {a0, a1, a2, a3, a4, a5};
#pragma unroll
    for (int kk = 0; kk < 6; kk++) {
      bf16x8 av = __builtin_bit_cast(bf16x8, af[kk]);
#pragma unroll
      for (int n = 0; n < 4; n++) {
        int j = n * 16 + l15;
        ushortx8 bu = *(const ushortx8*)(s_w1 + j * 384 + (((kk * 32 + csub) * 2) ^ ((j & 7) << 4)));
        acc[n] = __builtin_amdgcn_mfma_f32_16x16x32_bf16(av, __builtin_bit_cast(bf16x8, bu), acc[n], 0, 0, 0);
      }
    }
    // residual C-init from my_eh (ee rows) BEFORE overwriting with hid
    f32x4 acc2[4];
#pragma unroll
    for (int n = 0; n < 4; n++) {
#pragma unroll
      for (int i = 0; i < 4; i++) {
        int r = lq * 4 + i, col = n * 16 + l15;
        unsigned short ev = *(const unsigned short*)(my_eh + r * 128 + ((col * 2) ^ ((r & 7) << 4)));
        acc2[n][i] = bv2[n] + bf2f(ev);
      }
    }
    // relu(acc) -> hid into wave-private rows
#pragma unroll
    for (int n = 0; n < 4; n++) {
#pragma unroll
      for (int i = 0; i < 4; i++) {
        int r = lq * 4 + i, col = n * 16 + l15;
        *(unsigned short*)(my_eh + r * 128 + ((col * 2) ^ ((r & 7) << 4))) = f2bf(fmaxf(acc[n][i], 0.f));
      }
    }
#pragma unroll
    for (int kk = 0; kk < 2; kk++) {
      ushortx8 au = *(const ushortx8*)(my_eh + l15 * 128 + (((kk * 32 + csub) * 2) ^ rsw));
      bf16x8 av = __builtin_bit_cast(bf16x8, au);
#pragma unroll
      for (int n = 0; n < 4; n++) {
        int j = n * 16 + l15;
        ushortx8 bu = *(const ushortx8*)(s_w2 + j * 128 + (((kk * 32 + csub) * 2) ^ ((j & 7) << 4)));
        acc2[n] = __builtin_amdgcn_mfma_f32_16x16x32_bf16(av, __builtin_bit_cast(bf16x8, bu), acc2[n], 0, 0, 0);
      }
    }
#pragma unroll
    for (int n = 0; n < 4; n++) {
#pragma unroll
      for (int i = 0; i < 4; i++) {
        int r = lq * 4 + i, col = n * 16 + l15;
        *(unsigned short*)(my_eh + r * 128 + ((col * 2) ^ ((r & 7) << 4))) = f2bf(acc2[n][i]);
      }
    }
    ushortx8 q0 = *(const ushortx8*)(my_eh + l15 * 128 + ((lq * 32) ^ rsw));
    ushortx8 q1 = *(const ushortx8*)(my_eh + l15 * 128 + ((lq * 32 + 16) ^ rsw));
    ushortx8* op = (ushortx8*)(emsg + (size_t)sl * HD);
    op[lq * 2] = q0;
    op[lq * 2 + 1] = q1;
  }
}

// ---------------- per-deriv: agg + node MLP + decoder + RK4 accum + NEXT encoder ----------------
__global__ __launch_bounds__(256) void k_upd_enc(
    const int* __restrict__ row_ptr, const unsigned short* __restrict__ emsg,
    float* __restrict__ hbuf, unsigned short* __restrict__ h_bf,
    const char* __restrict__ wnm1sw, const char* __restrict__ wnm2sw,
    const char* __restrict__ wdec1sw, const char* __restrict__ wne2sw,
    const float* __restrict__ b_nm1, const float* __restrict__ b_nm2,
    const float* __restrict__ b_dec1, const float* __restrict__ b_dec2,
    const float* __restrict__ w_dec2, const float* __restrict__ amean, const float* __restrict__ astd,
    const float* __restrict__ w_ne1, const float* __restrict__ h_pre,
    const float* __restrict__ b_ne2, const float* __restrict__ vmean, const float* __restrict__ vstd,
    const float* __restrict__ tspan, int s, int k, int do_enc,
    const float* __restrict__ V0, float* __restrict__ vacc, float* __restrict__ pacc,
    const float* __restrict__ pos_prev, float* __restrict__ pos_next, float* __restrict__ vel_next) {
  __shared__ __align__(16) char s_w1[64 * 256];
  __shared__ __align__(16) char s_w2[64 * 128];
  __shared__ __align__(16) char s_wd1[64 * 128];
  __shared__ __align__(16) char s_w2e[64 * 128];
  __shared__ __align__(16) char s_ah[64 * 128];
  __shared__ float s_b1[64], s_b2[64], s_bd1[64], s_be2[64], s_wd2[192], s_w1e[192];
  __shared__ float s_vm[3], s_vs[3];
  int tid = threadIdx.x, n0b = blockIdx.x * 64;
  for (int c = tid; c < 1024; c += 256) ((ushortx8*)s_w1)[c] = ((const ushortx8*)wnm1sw)[c];
  for (int c = tid; c < 512; c += 256) ((ushortx8*)s_w2)[c] = ((const ushortx8*)wnm2sw)[c];
  for (int c = tid; c < 512; c += 256) ((ushortx8*)s_wd1)[c] = ((const ushortx8*)wdec1sw)[c];
  for (int c = tid; c < 512; c += 256) ((ushortx8*)s_w2e)[c] = ((const ushortx8*)wne2sw)[c];
  if (tid < 64) { s_b1[tid] = b_nm1[tid]; s_b2[tid] = b_nm2[tid]; s_bd1[tid] = b_dec1[tid]; s_be2[tid] = b_ne2[tid]; }
  if (tid < 192) { s_wd2[tid] = w_dec2[tid]; s_w1e[tid] = w_ne1[tid]; }
  if (tid < 3) { s_vm[tid] = vmean[tid]; s_vs[tid] = vstd[tid]; }

  int lane = tid & 63, wv = tid >> 6, l15 = lane & 15, lq = lane >> 4, csub = lq * 8;
  int row_l = wv * 16 + l15, rsw = (l15 & 7) << 4;
  int noderow = n0b + row_l;
  int ncl = noderow < NN ? noderow : NN - 1;
  ushortx8 afh0 = *(const ushortx8*)(h_bf + (size_t)ncl * 64 + csub);
  ushortx8 afh1 = *(const ushortx8*)(h_bf + (size_t)ncl * 64 + 32 + csub);

  // ---- agg: lane = (row in 0..7, ch-group in 0..7), 2 passes, no shuffles ----
  int arow = lane >> 3, ag = lane & 7;
#pragma unroll
  for (int p = 0; p < 2; p++) {
    int rl = wv * 16 + p * 8 + arow, node = n0b + rl;
    float sm[8] = {0.f, 0.f, 0.f, 0.f, 0.f, 0.f, 0.f, 0.f};
    if (node < NN) {
      int b = row_ptr[node], e = row_ptr[node + 1];
      for (int r = b; r < e; r++) {
        ushortx8 u = *(const ushortx8*)(emsg + (size_t)r * HD + ag * 8);
#pragma unroll
        for (int j = 0; j < 8; j++) sm[j] += bf2f(u[j]);
      }
    }
    ushortx8 u;
#pragma unroll
    for (int j = 0; j < 8; j++) u[j] = f2bf(sm[j]);
    *(ushortx8*)(s_ah + rl * 128 + ((ag * 16) ^ ((rl & 7) << 4))) = u;
  }
  __syncthreads();

  // ---- GEMM1: [h | agg] x wnm1 ----
  f32x4 acc[4];
#pragma unroll
  for (int n = 0; n < 4; n++) {
    float bv = s_b1[n * 16 + l15];
#pragma unroll
    for (int i = 0; i < 4; i++) acc[n][i] = bv;
  }
  ushortx8 af[4];
  af[0] = afh0; af[1] = afh1;
  af[2] = *(const ushortx8*)(s_ah + row_l * 128 + ((csub * 2) ^ rsw));
  af[3] = *(const ushortx8*)(s_ah + row_l * 128 + (((32 + csub) * 2) ^ rsw));
#pragma unroll
  for (int kk = 0; kk < 4; kk++) {
    bf16x8 av = __builtin_bit_cast(bf16x8, af[kk]);
#pragma unroll
    for (int n = 0; n < 4; n++) {
      int j = n * 16 + l15;
      ushortx8 bu = *(const ushortx8*)(s_w1 + j * 256 + (((kk * 32 + csub) * 2) ^ ((j & 7) << 4)));
      acc[n] = __builtin_amdgcn_mfma_f32_16x16x32_bf16(av, __builtin_bit_cast(bf16x8, bu), acc[n], 0, 0, 0);
    }
  }
#pragma unroll
  for (int n = 0; n < 4; n++) {
#pragma unroll
    for (int i = 0; i < 4; i++) {
      int r = wv * 16 + lq * 4 + i, col = n * 16 + l15;
      *(unsigned short*)(s_ah + r * 128 + ((col * 2) ^ ((r & 7) << 4))) = f2bf(fmaxf(acc[n][i], 0.f));
    }
  }
  // ---- GEMM2: hu = h(resid fp32) + b2 + hid x wnm2 ----
  f32x4 acc2[4];
#pragma unroll
  for (int n = 0; n < 4; n++) {
#pragma unroll
    for (int i = 0; i < 4; i++) {
      int r = wv * 16 + lq * 4 + i, col = n * 16 + l15;
      int rg = n0b + r; int rgc = rg < NN ? rg : NN - 1;
      acc2[n][i] = s_b2[col] + hbuf[(size_t)rgc * 64 + col];
    }
  }
#pragma unroll
  for (int kk = 0; kk < 2; kk++) {
    ushortx8 au = *(const ushortx8*)(s_ah + row_l * 128 + (((kk * 32 + csub) * 2) ^ rsw));
    bf16x8 av = __builtin_bit_cast(bf16x8, au);
#pragma unroll
    for (int n = 0; n < 4; n++) {
      int j = n * 16 + l15;
      ushortx8 bu = *(const ushortx8*)(s_w2 + j * 128 + (((kk * 32 + csub) * 2) ^ ((j & 7) << 4)));
      acc2[n] = __builtin_amdgcn_mfma_f32_16x16x32_bf16(av, __builtin_bit_cast(bf16x8, bu), acc2[n], 0, 0, 0);
    }
  }
#pragma unroll
  for (int n = 0; n < 4; n++) {
#pragma unroll
    for (int i = 0; i < 4; i++) {
      int r = wv * 16 + lq * 4 + i, col = n * 16 + l15;
      *(unsigned short*)(s_ah + r * 128 + ((col * 2) ^ ((r & 7) << 4))) = f2bf(acc2[n][i]);
    }
  }
  // ---- dec1 ----
  f32x4 acc3[4];
#pragma unroll
  for (int n = 0; n < 4; n++) {
    float bv = s_bd1[n * 16 + l15];
#pragma unroll
    for (int i = 0; i < 4; i++) acc3[n][i] = bv;
  }
#pragma unroll
  for (int kk = 0; kk < 2; kk++) {
    ushortx8 au = *(const ushortx8*)(s_ah + row_l * 128 + (((kk * 32 + csub) * 2) ^ rsw));
    bf16x8 av = __builtin_bit_cast(bf16x8, au);
#pragma unroll
    for (int n = 0; n < 4; n++) {
      int j = n * 16 + l15;
      ushortx8 bu = *(const ushortx8*)(s_wd1 + j * 128 + (((kk * 32 + csub) * 2) ^ ((j & 7) << 4)));
      acc3[n] = __builtin_amdgcn_mfma_f32_16x16x32_bf16(av, __builtin_bit_cast(bf16x8, bu), acc3[n], 0, 0, 0);
    }
  }
#pragma unroll
  for (int n = 0; n < 4; n++) {
#pragma unroll
    for (int i = 0; i < 4; i++) {
      int r = wv * 16 + lq * 4 + i, col = n * 16 + l15;
      *(unsigned short*)(s_ah + r * 128 + ((col * 2) ^ ((r & 7) << 4))) = f2bf(fmaxf(acc3[n][i], 0.f));
    }
  }
  // ---- dec2 ----
  ushortx8 u0 = *(const ushortx8*)(s_ah + row_l * 128 + ((lq * 32) ^ rsw));
  ushortx8 u1 = *(const ushortx8*)(s_ah + row_l * 128 + ((lq * 32 + 16) ^ rsw));
  float p[3] = {0.f, 0.f, 0.f};
#pragma unroll
  for (int i = 0; i < 8; i++) {
    float x0 = bf2f(u0[i]), x1 = bf2f(u1[i]);
    int c0 = lq * 16 + i, c1 = lq * 16 + 8 + i;
#pragma unroll
    for (int t = 0; t < 3; t++) p[t] += x0 * s_wd2[c0 * 3 + t] + x1 * s_wd2[c1 * 3 + t];
  }
#pragma unroll
  for (int t = 0; t < 3; t++) {
    p[t] += __shfl_xor(p[t], 16);
    p[t] += __shfl_xor(p[t], 32);
  }
  // ---- RK4 bookkeeping ----
  float dt = tspan[s + 1] - tspan[s];
  float o[3];
#pragma unroll
  for (int t = 0; t < 3; t++) o[t] = (p[t] + b_dec2[t]) * astd[t] + amean[t];
  const float ck = (k == 2) ? 1.0f : 0.5f;
  float vs[3] = {0.f, 0.f, 0.f};
  if (noderow < NN) {
    if (lq == 0) {
#pragma unroll
      for (int t = 0; t < 3; t++) {
        float v0v = V0[noderow * 3 + t];
        float wk = (k == 0 || k == 3) ? 1.f : 2.f;
        float va = (k == 0) ? o[t] : vacc[noderow * 3 + t] + wk * o[t];
        if (k < 3) {
          vacc[noderow * 3 + t] = va;
          vs[t] = v0v + ck * dt * o[t];
        } else {
          float vn = v0v + (dt / 6.f) * va;
          vel_next[noderow * 3 + t] = vn;
          vs[t] = vn;
        }
      }
    } else if (lq == 1) {
#pragma unroll
      for (int t = 0; t < 3; t++) {
        if (k < 3) {
          float v0v = V0[noderow * 3 + t];
          float vst = v0v + ck * dt * o[t];
          float pa;
          if (k == 0) pa = v0v + 2.f * vst;
          else pa = pacc[noderow * 3 + t] + ((k == 1) ? 2.f : 1.f) * vst;
          pacc[noderow * 3 + t] = pa;
        } else {
          pos_next[noderow * 3 + t] = pos_prev[noderow * 3 + t] + (dt / 6.f) * pacc[noderow * 3 + t];
        }
      }
    }
  }
  // ---- fused encoder for next stage ----
  if (do_enc) {
    for (int i = 0; i < 16; i++) {
      int rl = wv * 16 + i, node = n0b + rl;
      float v0s = __shfl(vs[0], i);
      float v1s = __shfl(vs[1], i);
      float v2s = __shfl(vs[2], i);
      float hv = 0.f;
      if (node < NN) {
        float vn0 = (v0s - s_vm[0]) / s_vs[0];
        float vn1 = (v1s - s_vm[1]) / s_vs[1];
        float vn2 = (v2s - s_vm[2]) / s_vs[2];
        float a = h_pre[(size_t)node * 64 + lane] + vn0 * s_w1e[lane] + vn1 * s_w1e[64 + lane] + vn2 * s_w1e[128 + lane];
        hv = fmaxf(a, 0.f);
      }
      *(unsigned short*)(s_ah + rl * 128 + ((lane * 2) ^ ((rl & 7) << 4))) = f2bf(hv);
    }
    f32x4 ae[4];
#pragma unroll
    for (int n = 0; n < 4; n++) {
      float bv = s_be2[n * 16 + l15];
#pragma unroll
      for (int i = 0; i < 4; i++) ae[n][i] = bv;
    }
#pragma unroll
    for (int kk = 0; kk < 2; kk++) {
      ushortx8 au = *(const ushortx8*)(s_ah + row_l * 128 + (((kk * 32 + csub) * 2) ^ rsw));
      bf16x8 av = __builtin_bit_cast(bf16x8, au);
#pragma unroll
      for (int n = 0; n < 4; n++) {
        int j = n * 16 + l15;
        ushortx8 bu = *(const ushortx8*)(s_w2e + j * 128 + (((kk * 32 + csub) * 2) ^ ((j & 7) << 4)));
        ae[n] = __builtin_amdgcn_mfma_f32_16x16x32_bf16(av, __builtin_bit_cast(bf16x8, bu), ae[n], 0, 0, 0);
      }
    }
#pragma unroll
    for (int n = 0; n < 4; n++) {
#pragma unroll
      for (int i = 0; i < 4; i++) {
        int r = wv * 16 + lq * 4 + i, rowg = n0b + r, col = n * 16 + l15;
        if (rowg < NN) hbuf[(size_t)rowg * 64 + col] = ae[n][i];
        *(unsigned short*)(s_ah + r * 128 + ((col * 2) ^ ((r & 7) << 4))) = f2bf(ae[n][i]);
      }
    }
    if (noderow < NN) {
      ushortx8 q0 = *(const ushortx8*)(s_ah + row_l * 128 + ((lq * 32) ^ rsw));
      ushortx8 q1 = *(const ushortx8*)(s_ah + row_l * 128 + ((lq * 32 + 16) ^ rsw));
      ushortx8* op = (ushortx8*)(h_bf + (size_t)noderow * 64);
      op[lq * 2] = q0;
      op[lq * 2 + 1] = q1;
    }
  }
}

extern "C" void kernel_launch(void* const* d_in, const int* in_sizes, int n_in,
                              void* d_out, int out_size, void* d_ws, size_t ws_size,
                              hipStream_t stream) {
  (void)in_sizes; (void)n_in; (void)out_size; (void)ws_size;
  const float* world_pos = (const float*)d_in[0];
  const float* velocity  = (const float*)d_in[1];
  const int*   eidx      = (const int*)d_in[2];
  const float* eattr     = (const float*)d_in[3];
  const float* youngs    = (const float*)d_in[4];
  const float* onehot    = (const float*)d_in[5];
  const float* tspan     = (const float*)d_in[7];
  const float* ym        = (const float*)d_in[8];
  const float* ys        = (const float*)d_in[9];
  const float* emean     = (const float*)d_in[10];
  const float* estd      = (const float*)d_in[11];
  const float* vmean     = (const float*)d_in[12];
  const float* vstd      = (const float*)d_in[13];
  const float* amean     = (const float*)d_in[14];
  const float* astd      = (const float*)d_in[15];
  const float* w_ne1 = (const float*)d_in[16]; const float* b_ne1 = (const float*)d_in[17];
  const float* w_ne2 = (const float*)d_in[18]; const float* b_ne2 = (const float*)d_in[19];
  const float* w_ee1 = (const float*)d_in[20]; const float* b_ee1 = (const float*)d_in[21];
  const float* w_ee2 = (const float*)d_in[22]; const float* b_ee2 = (const float*)d_in[23];
  const float* w_em1 = (const float*)d_in[24]; const float* b_em1 = (const float*)d_in[25];
  const float* w_em2 = (const float*)d_in[26]; const float* b_em2 = (const float*)d_in[27];
  const float* w_nm1 = (const float*)d_in[28]; const float* b_nm1 = (const float*)d_in[29];
  const float* w_nm2 = (const float*)d_in[30]; const float* b_nm2 = (const float*)d_in[31];
  const float* w_dec1 = (const float*)d_in[32]; const float* b_dec1 = (const float*)d_in[33];
  const float* w_dec2 = (const float*)d_in[34]; const float* b_dec2 = (const float*)d_in[35];

  char* ws = (char*)d_ws;
  float* h_pre  = (float*)ws; ws += (size_t)NN * HD * 4;
  float* hbuf   = (float*)ws; ws += (size_t)NN * HD * 4;
  char* eenc_sw = ws; ws += (size_t)NE * 128;
  unsigned short* emsg_bf = (unsigned short*)ws; ws += (size_t)NE * HD * 2;
  unsigned short* h_bf    = (unsigned short*)ws; ws += (size_t)NN * HD * 2;
  char* w1em  = ws; ws += 64 * 384;
  char* w2em  = ws; ws += 64 * 128;
  char* wnm1s = ws; ws += 64 * 256;
  char* wnm2s = ws; ws += 64 * 128;
  char* wdec1s = ws; ws += 64 * 128;
  char* wne2s = ws; ws += 64 * 128;
  char* wee2s = ws; ws += 64 * 128;
  float* vacc = (float*)ws; ws += (size_t)NN * 3 * 4;
  float* pacc = (float*)ws; ws += (size_t)NN * 3 * 4;
  int* counts  = (int*)ws; ws += (size_t)NN * 4;
  int* fill    = (int*)ws; ws += (size_t)NN * 4;
  int* slot    = (int*)ws; ws += (size_t)NE * 4;
  int* row_ptr = (int*)ws; ws += (size_t)(NN + 1) * 4;
  int* bsums   = (int*)ws; ws += (size_t)128 * 4;

  float* PO = (float*)d_out;
  float* VO = PO + (size_t)TT * NN * 3;

  // --- once-per-launch precompute ---
  k_prep<<<(NN * HD) / 256, 256, 0, stream>>>(world_pos, velocity, PO, VO, counts, fill,
                                              youngs, onehot, ym, ys, w_ne1, b_ne1, h_pre,
                                              w_em1, w_em2, w_nm1, w_nm2, w_dec1, w_ne2, w_ee2,
                                              w1em, w2em, wnm1s, wnm2s, wdec1s, wne2s, wee2s);
  k_edge_enc_mfma<<<NE / 64, 256, 0, stream>>>(eattr, emean, estd, w_ee1, b_ee1, wee2s, b_ee2, eenc_sw);
  k_count<<<NE / 256, 256, 0, stream>>>(eidx, counts);
  k_scanA<<<SCAN_NB, 256, 0, stream>>>(counts, row_ptr, bsums);
  k_scanB<<<1, 128, 0, stream>>>(bsums);
  k_scanC<<<SCAN_NB, 256, 0, stream>>>(row_ptr, bsums);
  k_place<<<NE / 256, 256, 0, stream>>>(eidx, row_ptr, fill, slot);

  const int NBLK = (NN + 63) / 64;
  k_enc_mfma<<<NBLK, 256, 0, stream>>>(velocity, vmean, vstd, w_ne1, h_pre, wne2s, b_ne2, hbuf, h_bf);

  for (int s = 0; s < TT - 1; s++) {
    const float* V0 = VO + (size_t)s * NN * 3;
    const float* pos_prev = PO + (size_t)s * NN * 3;
    float* pos_next = PO + (size_t)(s + 1) * NN * 3;
    float* vel_next = VO + (size_t)(s + 1) * NN * 3;
    for (int k = 0; k < 4; k++) {
      k_edge_mfma<<<EDGE_GRID, 256, 0, stream>>>(eidx, slot, h_bf, eenc_sw, w1em, w2em,
                                                 b_em1, b_em2, emsg_bf);
      int do_enc = !(s == TT - 2 && k == 3);
      k_upd_enc<<<NBLK, 256, 0, stream>>>(row_ptr, emsg_bf, hbuf, h_bf,
                                          wnm1s, wnm2s, wdec1s, wne2s,
                                          b_nm1, b_nm2, b_dec1, b_dec2, w_dec2, amean, astd,
                                          w_ne1, h_pre, b_ne2, vmean, vstd,
                                          tspan, s, k, do_enc,
                                          V0, vacc, pacc, pos_prev, pos_next, vel_next);
    }
  }
}

// Round 9
// 422.515 us; speedup vs baseline: 1.8646x; 1.8646x over previous
//
#include <hip/hip_runtime.h>
#include <hip/hip_bf16.h>

#define NN 20000
#define NE 160000
#define HD 64
#define TT 3

typedef unsigned short ushortx8 __attribute__((ext_vector_type(8)));
typedef float f32x4 __attribute__((ext_vector_type(4)));
typedef __bf16 bf16x8 __attribute__((ext_vector_type(8)));

__device__ __forceinline__ unsigned short f2bf(float f) {
  unsigned int x = __float_as_uint(f);
  unsigned int r = (x + 0x7fffu + ((x >> 16) & 1u)) >> 16;  // RNE, finite inputs
  return (unsigned short)r;
}
__device__ __forceinline__ float bf2f(unsigned short u) {
  return __uint_as_float(((unsigned int)u) << 16);
}

// ---------------- fused precompute: init out, zero counts, h_pre, weight prep ----------------
__global__ __launch_bounds__(256) void k_prep(const float* __restrict__ wp,
    const float* __restrict__ vel, float* __restrict__ PO, float* __restrict__ VO,
    int* __restrict__ counts, int* __restrict__ fill,
    const float* __restrict__ youngs, const float* __restrict__ onehot,
    const float* __restrict__ ym, const float* __restrict__ ys,
    const float* __restrict__ w_ne1, const float* __restrict__ b_ne1, float* __restrict__ h_pre,
    const float* __restrict__ w_em1, const float* __restrict__ w_em2,
    const float* __restrict__ w_nm1, const float* __restrict__ w_nm2,
    const float* __restrict__ w_dec1, const float* __restrict__ w_ne2, const float* __restrict__ w_ee2,
    char* __restrict__ w1em, char* __restrict__ w2em, char* __restrict__ wnm1,
    char* __restrict__ wnm2, char* __restrict__ wdec1, char* __restrict__ wne2,
    char* __restrict__ wee2) {
  int idx = blockIdx.x * 256 + threadIdx.x;
  if (idx < NN * 3) { PO[idx] = wp[idx]; VO[idx] = vel[idx]; }
  if (idx < NN) { counts[idx] = 0; fill[idx] = 0; }
  {  // h_pre (all idx < NN*HD; grid == NN*HD/256)
    int n = idx >> 6, j = idx & 63;
    float a = b_ne1[j];
    float yn = (youngs[n] - ym[0]) / ys[0];
    a += yn * w_ne1[3 * HD + j];
#pragma unroll
    for (int k = 0; k < 9; k++) a += onehot[n * 9 + k] * w_ne1[(4 + k) * HD + j];
    h_pre[idx] = a;
  }
  int w = idx;
  if (w < 12288) {
    int j = w / 192, k = w % 192;
    *(unsigned short*)(w1em + j * 384 + ((k * 2) ^ ((j & 7) << 4))) = f2bf(w_em1[k * 64 + j]);
    return;
  }
  w -= 12288;
  if (w < 4096) {
    int j = w >> 6, k = w & 63;
    *(unsigned short*)(w2em + j * 128 + ((k * 2) ^ ((j & 7) << 4))) = f2bf(w_em2[k * 64 + j]);
    return;
  }
  w -= 4096;
  if (w < 8192) {
    int j = w >> 7, k = w & 127;
    *(unsigned short*)(wnm1 + j * 256 + ((k * 2) ^ ((j & 7) << 4))) = f2bf(w_nm1[k * 64 + j]);
    return;
  }
  w -= 8192;
  if (w < 4096) {
    int j = w >> 6, k = w & 63;
    *(unsigned short*)(wnm2 + j * 128 + ((k * 2) ^ ((j & 7) << 4))) = f2bf(w_nm2[k * 64 + j]);
    return;
  }
  w -= 4096;
  if (w < 4096) {
    int j = w >> 6, k = w & 63;
    *(unsigned short*)(wdec1 + j * 128 + ((k * 2) ^ ((j & 7) << 4))) = f2bf(w_dec1[k * 64 + j]);
    return;
  }
  w -= 4096;
  if (w < 4096) {
    int j = w >> 6, k = w & 63;
    *(unsigned short*)(wne2 + j * 128 + ((k * 2) ^ ((j & 7) << 4))) = f2bf(w_ne2[k * 64 + j]);
    return;
  }
  w -= 4096;
  if (w < 4096) {
    int j = w >> 6, k = w & 63;
    *(unsigned short*)(wee2 + j * 128 + ((k * 2) ^ ((j & 7) << 4))) = f2bf(w_ee2[k * 64 + j]);
    return;
  }
}

// ---------------- static edge encoder via MFMA (once) -> pre-swizzled bf16 ----------------
__global__ __launch_bounds__(256) void k_edge_enc_mfma(const float* __restrict__ eattr,
    const float* __restrict__ emean, const float* __restrict__ estd,
    const float* __restrict__ w_ee1, const float* __restrict__ b_ee1,
    const char* __restrict__ wee2sw, const float* __restrict__ b_ee2,
    char* __restrict__ eenc_sw) {
  __shared__ __align__(16) char s_w2[64 * 128];
  __shared__ __align__(16) char s_hid[64 * 128];
  __shared__ float s_w1[4 * 64], s_b1[64], s_b2[64], s_m[4], s_s[4];
  int tid = threadIdx.x, e0b = blockIdx.x * 64;
  for (int c = tid; c < 512; c += 256) ((ushortx8*)s_w2)[c] = ((const ushortx8*)wee2sw)[c];
  if (tid < 256) s_w1[tid] = w_ee1[tid];
  if (tid < 64) { s_b1[tid] = b_ee1[tid]; s_b2[tid] = b_ee2[tid]; }
  if (tid < 4) { s_m[tid] = emean[tid]; s_s[tid] = estd[tid]; }
  __syncthreads();
  int lane = tid & 63, wv = tid >> 6, l15 = lane & 15, lq = lane >> 4, csub = lq * 8;
  int row_l = wv * 16 + l15, rsw = (l15 & 7) << 4;
  int erow = e0b + row_l;
  float4 at = ((const float4*)eattr)[erow];
  float x0 = (at.x - s_m[0]) / s_s[0];
  float x1 = (at.y - s_m[1]) / s_s[1];
  float x2 = (at.z - s_m[2]) / s_s[2];
  float x3 = (at.w - s_m[3]) / s_s[3];
#pragma unroll 4
  for (int i = 0; i < 16; i++) {
    int rl = wv * 16 + i;
    float y0 = __shfl(x0, i), y1 = __shfl(x1, i), y2 = __shfl(x2, i), y3 = __shfl(x3, i);
    float a = s_b1[lane] + y0 * s_w1[lane] + y1 * s_w1[64 + lane] + y2 * s_w1[128 + lane] + y3 * s_w1[192 + lane];
    *(unsigned short*)(s_hid + rl * 128 + ((lane * 2) ^ ((rl & 7) << 4))) = f2bf(fmaxf(a, 0.f));
  }
  f32x4 acc[4];
#pragma unroll
  for (int n = 0; n < 4; n++) {
    float bv = s_b2[n * 16 + l15];
#pragma unroll
    for (int i = 0; i < 4; i++) acc[n][i] = bv;
  }
#pragma unroll
  for (int kk = 0; kk < 2; kk++) {
    ushortx8 au = *(const ushortx8*)(s_hid + row_l * 128 + (((kk * 32 + csub) * 2) ^ rsw));
    bf16x8 av = __builtin_bit_cast(bf16x8, au);
#pragma unroll
    for (int n = 0; n < 4; n++) {
      int j = n * 16 + l15;
      ushortx8 bu = *(const ushortx8*)(s_w2 + j * 128 + (((kk * 32 + csub) * 2) ^ ((j & 7) << 4)));
      acc[n] = __builtin_amdgcn_mfma_f32_16x16x32_bf16(av, __builtin_bit_cast(bf16x8, bu), acc[n], 0, 0, 0);
    }
  }
#pragma unroll
  for (int n = 0; n < 4; n++) {
#pragma unroll
    for (int i = 0; i < 4; i++) {
      int r = wv * 16 + lq * 4 + i, col = n * 16 + l15;
      *(unsigned short*)(s_hid + r * 128 + ((col * 2) ^ ((r & 7) << 4))) = f2bf(acc[n][i]);
    }
  }
  ushortx8 q0 = *(const ushortx8*)(s_hid + row_l * 128 + lq * 32);
  ushortx8 q1 = *(const ushortx8*)(s_hid + row_l * 128 + lq * 32 + 16);
  *(ushortx8*)(eenc_sw + (size_t)erow * 128 + lq * 32) = q0;
  *(ushortx8*)(eenc_sw + (size_t)erow * 128 + lq * 32 + 16) = q1;
}

// ---------------- CSR build ----------------
__global__ __launch_bounds__(256) void k_count(const int* __restrict__ eidx, int* __restrict__ counts) {
  int e = blockIdx.x * 256 + threadIdx.x;
  if (e < NE) atomicAdd(&counts[eidx[NE + e]], 1);
}

#define SCAN_NB ((NN + 255) / 256)
__global__ __launch_bounds__(256) void k_scanA(const int* __restrict__ counts,
    int* __restrict__ row_ptr, int* __restrict__ bsums) {
  __shared__ int tmp[256];
  int tid = threadIdx.x;
  int g = blockIdx.x * 256 + tid;
  int v = (g < NN) ? counts[g] : 0;
  tmp[tid] = v;
  __syncthreads();
#pragma unroll
  for (int off = 1; off < 256; off <<= 1) {
    int t = (tid >= off) ? tmp[tid - off] : 0;
    __syncthreads();
    tmp[tid] += t;
    __syncthreads();
  }
  if (g < NN) row_ptr[g] = tmp[tid] - v;
  if (tid == 255) bsums[blockIdx.x] = tmp[255];
}

__global__ __launch_bounds__(128) void k_scanB(int* __restrict__ bsums) {
  __shared__ int tmp[128];
  int tid = threadIdx.x;
  int v = (tid < SCAN_NB) ? bsums[tid] : 0;
  tmp[tid] = v;
  __syncthreads();
#pragma unroll
  for (int off = 1; off < 128; off <<= 1) {
    int t = (tid >= off) ? tmp[tid - off] : 0;
    __syncthreads();
    tmp[tid] += t;
    __syncthreads();
  }
  if (tid < SCAN_NB) bsums[tid] = tmp[tid] - v;
}

__global__ __launch_bounds__(256) void k_scanC(int* __restrict__ row_ptr, const int* __restrict__ bsums) {
  int g = blockIdx.x * 256 + threadIdx.x;
  if (g < NN) row_ptr[g] += bsums[blockIdx.x];
  if (g == 0) row_ptr[NN] = NE;
}

__global__ __launch_bounds__(256) void k_place(const int* __restrict__ eidx,
    const int* __restrict__ row_ptr, int* __restrict__ fill, int* __restrict__ slot) {
  int e = blockIdx.x * 256 + threadIdx.x;
  if (e >= NE) return;
  int d = eidx[NE + e];
  int f = atomicAdd(&fill[d], 1);
  slot[e] = row_ptr[d] + f;
}

// ---------------- initial node encoder (t=0 only) ----------------
__global__ __launch_bounds__(256) void k_enc_mfma(const float* __restrict__ vel,
    const float* __restrict__ vmean, const float* __restrict__ vstd,
    const float* __restrict__ w_ne1, const float* __restrict__ h_pre,
    const char* __restrict__ wne2sw, const float* __restrict__ b_ne2,
    float* __restrict__ h, unsigned short* __restrict__ h_bf) {
  __shared__ __align__(16) char s_w2[64 * 128];
  __shared__ __align__(16) char s_hid[64 * 128];
  __shared__ float s_w1[3 * 64], s_b2[64], s_vm[3], s_vs[3];
  int tid = threadIdx.x, n0b = blockIdx.x * 64;
  for (int c = tid; c < 512; c += 256) ((ushortx8*)s_w2)[c] = ((const ushortx8*)wne2sw)[c];
  if (tid < 192) s_w1[tid] = w_ne1[tid];
  if (tid < 64) s_b2[tid] = b_ne2[tid];
  if (tid < 3) { s_vm[tid] = vmean[tid]; s_vs[tid] = vstd[tid]; }
  __syncthreads();
  int lane = tid & 63, wv = tid >> 6, l15 = lane & 15, lq = lane >> 4, csub = lq * 8;
#pragma unroll 4
  for (int i = 0; i < 16; i++) {
    int rl = wv * 16 + i, node = n0b + rl;
    float hv = 0.f;
    if (node < NN) {
      float v0 = (vel[node * 3 + 0] - s_vm[0]) / s_vs[0];
      float v1 = (vel[node * 3 + 1] - s_vm[1]) / s_vs[1];
      float v2 = (vel[node * 3 + 2] - s_vm[2]) / s_vs[2];
      float a = h_pre[(size_t)node * 64 + lane] + v0 * s_w1[lane] + v1 * s_w1[64 + lane] + v2 * s_w1[128 + lane];
      hv = fmaxf(a, 0.f);
    }
    *(unsigned short*)(s_hid + rl * 128 + ((lane * 2) ^ ((rl & 7) << 4))) = f2bf(hv);
  }
  int row_l = wv * 16 + l15, rsw = (l15 & 7) << 4;
  f32x4 acc[4];
#pragma unroll
  for (int n = 0; n < 4; n++) {
    float bv = s_b2[n * 16 + l15];
#pragma unroll
    for (int i = 0; i < 4; i++) acc[n][i] = bv;
  }
#pragma unroll
  for (int kk = 0; kk < 2; kk++) {
    ushortx8 au = *(const ushortx8*)(s_hid + row_l * 128 + (((kk * 32 + csub) * 2) ^ rsw));
    bf16x8 av = __builtin_bit_cast(bf16x8, au);
#pragma unroll
    for (int n = 0; n < 4; n++) {
      int j = n * 16 + l15;
      ushortx8 bu = *(const ushortx8*)(s_w2 + j * 128 + (((kk * 32 + csub) * 2) ^ ((j & 7) << 4)));
      acc[n] = __builtin_amdgcn_mfma_f32_16x16x32_bf16(av, __builtin_bit_cast(bf16x8, bu), acc[n], 0, 0, 0);
    }
  }
#pragma unroll
  for (int n = 0; n < 4; n++) {
#pragma unroll
    for (int i = 0; i < 4; i++) {
      int r = wv * 16 + lq * 4 + i, rowg = n0b + r, col = n * 16 + l15;
      if (rowg < NN) h[(size_t)rowg * 64 + col] = acc[n][i];
      *(unsigned short*)(s_hid + r * 128 + ((col * 2) ^ ((r & 7) << 4))) = f2bf(acc[n][i]);
    }
  }
  int noderow = n0b + row_l;
  if (noderow < NN) {
    ushortx8 q0 = *(const ushortx8*)(s_hid + row_l * 128 + ((lq * 32) ^ rsw));
    ushortx8 q1 = *(const ushortx8*)(s_hid + row_l * 128 + ((lq * 32 + 16) ^ rsw));
    ushortx8* op = (ushortx8*)(h_bf + (size_t)noderow * 64);
    op[lq * 2] = q0;
    op[lq * 2 + 1] = q1;
  }
}

// ---------------- per-deriv: edge message MLP via MFMA, persistent + staged eenc ----------------
// R7-proven structure: block-coalesced LDS staging + 2 barriers/tile (lockstep keeps
// L2 traffic coherent) + register prefetch of next tile under this tile's MFMAs.
#define EDGE_GRID 1024
__global__ __launch_bounds__(256, 4) void k_edge_mfma(
    const int* __restrict__ eidx, const int* __restrict__ slot,
    const unsigned short* __restrict__ h_bf, const char* __restrict__ eenc_sw,
    const char* __restrict__ w1sw, const char* __restrict__ w2sw,
    const float* __restrict__ b_em1, const float* __restrict__ b_em2,
    unsigned short* __restrict__ emsg) {
  __shared__ __align__(16) char s_w1[64 * 384];  // 24KB
  __shared__ __align__(16) char s_w2[64 * 128];  // 8KB
  __shared__ __align__(16) char s_eh[64 * 128];  // 8KB: ee tile / hid / out overlay
  int tid = threadIdx.x;
  int lane = tid & 63, wv = tid >> 6, l15 = lane & 15, lq = lane >> 4, csub = lq * 8;
  int erow_loc = wv * 16 + l15;
  int rsw = (l15 & 7) << 4;
  for (int c = tid; c < 1536; c += 256) ((ushortx8*)s_w1)[c] = ((const ushortx8*)w1sw)[c];
  for (int c = tid; c < 512; c += 256) ((ushortx8*)s_w2)[c] = ((const ushortx8*)w2sw)[c];
  float bv1[4], bv2[4];
#pragma unroll
  for (int n = 0; n < 4; n++) { bv1[n] = b_em1[n * 16 + l15]; bv2[n] = b_em2[n * 16 + l15]; }

  const int NT = NE / 64;
  ushortx8 stg0, stg1;
  {
    const ushortx8* src = (const ushortx8*)(eenc_sw + (size_t)blockIdx.x * 64 * 128);
    stg0 = src[tid];
    stg1 = src[tid + 256];
  }
  for (int t = blockIdx.x; t < NT; t += EDGE_GRID) {
    int e0b = t * 64;
    int eg = e0b + erow_loc;
    int sidx = eidx[eg], didx = eidx[NE + eg], sl = slot[eg];
    const ushortx8* hs = (const ushortx8*)(h_bf + (size_t)sidx * HD);
    const ushortx8* hd = (const ushortx8*)(h_bf + (size_t)didx * HD);
    ushortx8 a2 = hs[lq];
    ushortx8 a3 = hs[4 + lq];
    ushortx8 a4 = hd[lq];
    ushortx8 a5 = hd[4 + lq];
    __syncthreads();  // prev tile done with s_eh (1st iter: weights visible)
    ((ushortx8*)s_eh)[tid] = stg0;
    ((ushortx8*)s_eh)[tid + 256] = stg1;
    __syncthreads();  // s_eh ready
    int tn = t + EDGE_GRID;
    if (tn < NT) {  // issue next tile's loads; they complete under the MFMAs below
      const ushortx8* srcn = (const ushortx8*)(eenc_sw + (size_t)tn * 64 * 128);
      stg0 = srcn[tid];
      stg1 = srcn[tid + 256];
    }
    ushortx8 a0 = *(const ushortx8*)(s_eh + erow_loc * 128 + ((csub * 2) ^ rsw));
    ushortx8 a1 = *(const ushortx8*)(s_eh + erow_loc * 128 + ((64 + csub * 2) ^ rsw));
    f32x4 acc[4];
#pragma unroll
    for (int n = 0; n < 4; n++) {
#pragma unroll
      for (int i = 0; i < 4; i++) acc[n][i] = bv1[n];
    }
    ushortx8 af[6] = {a0, a1, a2, a3, a4, a5};
#pragma unroll
    for (int kk = 0; kk < 6; kk++) {
      bf16x8 av = __builtin_bit_cast(bf16x8, af[kk]);
#pragma unroll
      for (int n = 0; n < 4; n++) {
        int j = n * 16 + l15;
        ushortx8 bu = *(const ushortx8*)(s_w1 + j * 384 + (((kk * 32 + csub) * 2) ^ ((j & 7) << 4)));
        acc[n] = __builtin_amdgcn_mfma_f32_16x16x32_bf16(av, __builtin_bit_cast(bf16x8, bu), acc[n], 0, 0, 0);
      }
    }
    // residual C-init from s_eh (ee) BEFORE overwriting with hid (own-wave rows only)
    f32x4 acc2[4];
#pragma unroll
    for (int n = 0; n < 4; n++) {
#pragma unroll
      for (int i = 0; i < 4; i++) {
        int r = wv * 16 + lq * 4 + i, col = n * 16 + l15;
        unsigned short ev = *(const unsigned short*)(s_eh + r * 128 + ((col * 2) ^ ((r & 7) << 4)));
        acc2[n][i] = bv2[n] + bf2f(ev);
      }
    }
    // relu(acc) -> hid into own-wave rows
#pragma unroll
    for (int n = 0; n < 4; n++) {
#pragma unroll
      for (int i = 0; i < 4; i++) {
        int r = wv * 16 + lq * 4 + i, col = n * 16 + l15;
        *(unsigned short*)(s_eh + r * 128 + ((col * 2) ^ ((r & 7) << 4))) = f2bf(fmaxf(acc[n][i], 0.f));
      }
    }
#pragma unroll
    for (int kk = 0; kk < 2; kk++) {
      ushortx8 au = *(const ushortx8*)(s_eh + erow_loc * 128 + (((kk * 32 + csub) * 2) ^ rsw));
      bf16x8 av = __builtin_bit_cast(bf16x8, au);
#pragma unroll
      for (int n = 0; n < 4; n++) {
        int j = n * 16 + l15;
        ushortx8 bu = *(const ushortx8*)(s_w2 + j * 128 + (((kk * 32 + csub) * 2) ^ ((j & 7) << 4)));
        acc2[n] = __builtin_amdgcn_mfma_f32_16x16x32_bf16(av, __builtin_bit_cast(bf16x8, bu), acc2[n], 0, 0, 0);
      }
    }
#pragma unroll
    for (int n = 0; n < 4; n++) {
#pragma unroll
      for (int i = 0; i < 4; i++) {
        int r = wv * 16 + lq * 4 + i, col = n * 16 + l15;
        *(unsigned short*)(s_eh + r * 128 + ((col * 2) ^ ((r & 7) << 4))) = f2bf(acc2[n][i]);
      }
    }
    ushortx8 q0 = *(const ushortx8*)(s_eh + erow_loc * 128 + ((lq * 32) ^ rsw));
    ushortx8 q1 = *(const ushortx8*)(s_eh + erow_loc * 128 + ((lq * 32 + 16) ^ rsw));
    ushortx8* op = (ushortx8*)(emsg + (size_t)sl * HD);
    op[lq * 2] = q0;
    op[lq * 2 + 1] = q1;
  }
}

// ---------------- per-deriv: agg + node MLP + decoder + RK4 accum + NEXT encoder ----------------
// 128 threads / 2 waves / 32 nodes per block -> 625 blocks (was 313) for latency hiding.
__global__ __launch_bounds__(128) void k_upd_enc(
    const int* __restrict__ row_ptr, const unsigned short* __restrict__ emsg,
    float* __restrict__ hbuf, unsigned short* __restrict__ h_bf,
    const char* __restrict__ wnm1sw, const char* __restrict__ wnm2sw,
    const char* __restrict__ wdec1sw, const char* __restrict__ wne2sw,
    const float* __restrict__ b_nm1, const float* __restrict__ b_nm2,
    const float* __restrict__ b_dec1, const float* __restrict__ b_dec2,
    const float* __restrict__ w_dec2, const float* __restrict__ amean, const float* __restrict__ astd,
    const float* __restrict__ w_ne1, const float* __restrict__ h_pre,
    const float* __restrict__ b_ne2, const float* __restrict__ vmean, const float* __restrict__ vstd,
    const float* __restrict__ tspan, int s, int k, int do_enc,
    const float* __restrict__ V0, float* __restrict__ vacc, float* __restrict__ pacc,
    const float* __restrict__ pos_prev, float* __restrict__ pos_next, float* __restrict__ vel_next) {
  __shared__ __align__(16) char s_w1[64 * 256];   // 16KB  wnm1
  __shared__ __align__(16) char s_w2[64 * 128];   // 8KB   wnm2
  __shared__ __align__(16) char s_wd1[64 * 128];  // 8KB   wdec1
  __shared__ __align__(16) char s_w2e[64 * 128];  // 8KB   wne2
  __shared__ __align__(16) char s_ah[32 * 128];   // 4KB   agg -> hid overlay (wave-private rows)
  __shared__ float s_b1[64], s_b2[64], s_bd1[64], s_be2[64], s_wd2[192], s_w1e[192];
  __shared__ float s_vm[3], s_vs[3];
  int tid = threadIdx.x, n0b = blockIdx.x * 32;
  for (int c = tid; c < 1024; c += 128) ((ushortx8*)s_w1)[c] = ((const ushortx8*)wnm1sw)[c];
  for (int c = tid; c < 512; c += 128) ((ushortx8*)s_w2)[c] = ((const ushortx8*)wnm2sw)[c];
  for (int c = tid; c < 512; c += 128) ((ushortx8*)s_wd1)[c] = ((const ushortx8*)wdec1sw)[c];
  for (int c = tid; c < 512; c += 128) ((ushortx8*)s_w2e)[c] = ((const ushortx8*)wne2sw)[c];
  if (tid < 64) { s_b1[tid] = b_nm1[tid]; s_b2[tid] = b_nm2[tid]; s_bd1[tid] = b_dec1[tid]; s_be2[tid] = b_ne2[tid]; }
  for (int i = tid; i < 192; i += 128) { s_wd2[i] = w_dec2[i]; s_w1e[i] = w_ne1[i]; }
  if (tid < 3) { s_vm[tid] = vmean[tid]; s_vs[tid] = vstd[tid]; }

  int lane = tid & 63, wv = tid >> 6, l15 = lane & 15, lq = lane >> 4, csub = lq * 8;
  int row_l = wv * 16 + l15, rsw = (l15 & 7) << 4;
  int noderow = n0b + row_l;
  int ncl = noderow < NN ? noderow : NN - 1;
  ushortx8 afh0 = *(const ushortx8*)(h_bf + (size_t)ncl * 64 + csub);
  ushortx8 afh1 = *(const ushortx8*)(h_bf + (size_t)ncl * 64 + 32 + csub);

  // ---- agg: lane = (row in 0..7, ch-group in 0..7), 2 passes, no shuffles ----
  int arow = lane >> 3, ag = lane & 7;
#pragma unroll
  for (int p = 0; p < 2; p++) {
    int rl = wv * 16 + p * 8 + arow, node = n0b + rl;
    float sm[8] = {0.f, 0.f, 0.f, 0.f, 0.f, 0.f, 0.f, 0.f};
    if (node < NN) {
      int b = row_ptr[node], e = row_ptr[node + 1];
      for (int r = b; r < e; r++) {
        ushortx8 u = *(const ushortx8*)(emsg + (size_t)r * HD + ag * 8);
#pragma unroll
        for (int j = 0; j < 8; j++) sm[j] += bf2f(u[j]);
      }
    }
    ushortx8 u;
#pragma unroll
    for (int j = 0; j < 8; j++) u[j] = f2bf(sm[j]);
    *(ushortx8*)(s_ah + rl * 128 + ((ag * 16) ^ ((rl & 7) << 4))) = u;
  }
  __syncthreads();

  // ---- GEMM1: [h | agg] x wnm1 ----
  f32x4 acc[4];
#pragma unroll
  for (int n = 0; n < 4; n++) {
    float bv = s_b1[n * 16 + l15];
#pragma unroll
    for (int i = 0; i < 4; i++) acc[n][i] = bv;
  }
  ushortx8 af[4];
  af[0] = afh0; af[1] = afh1;
  af[2] = *(const ushortx8*)(s_ah + row_l * 128 + ((csub * 2) ^ rsw));
  af[3] = *(const ushortx8*)(s_ah + row_l * 128 + (((32 + csub) * 2) ^ rsw));
#pragma unroll
  for (int kk = 0; kk < 4; kk++) {
    bf16x8 av = __builtin_bit_cast(bf16x8, af[kk]);
#pragma unroll
    for (int n = 0; n < 4; n++) {
      int j = n * 16 + l15;
      ushortx8 bu = *(const ushortx8*)(s_w1 + j * 256 + (((kk * 32 + csub) * 2) ^ ((j & 7) << 4)));
      acc[n] = __builtin_amdgcn_mfma_f32_16x16x32_bf16(av, __builtin_bit_cast(bf16x8, bu), acc[n], 0, 0, 0);
    }
  }
#pragma unroll
  for (int n = 0; n < 4; n++) {
#pragma unroll
    for (int i = 0; i < 4; i++) {
      int r = wv * 16 + lq * 4 + i, col = n * 16 + l15;
      *(unsigned short*)(s_ah + r * 128 + ((col * 2) ^ ((r & 7) << 4))) = f2bf(fmaxf(acc[n][i], 0.f));
    }
  }
  // ---- GEMM2: hu = h(resid fp32) + b2 + hid x wnm2 ----
  f32x4 acc2[4];
#pragma unroll
  for (int n = 0; n < 4; n++) {
#pragma unroll
    for (int i = 0; i < 4; i++) {
      int r = wv * 16 + lq * 4 + i, col = n * 16 + l15;
      int rg = n0b + r; int rgc = rg < NN ? rg : NN - 1;
      acc2[n][i] = s_b2[col] + hbuf[(size_t)rgc * 64 + col];
    }
  }
#pragma unroll
  for (int kk = 0; kk < 2; kk++) {
    ushortx8 au = *(const ushortx8*)(s_ah + row_l * 128 + (((kk * 32 + csub) * 2) ^ rsw));
    bf16x8 av = __builtin_bit_cast(bf16x8, au);
#pragma unroll
    for (int n = 0; n < 4; n++) {
      int j = n * 16 + l15;
      ushortx8 bu = *(const ushortx8*)(s_w2 + j * 128 + (((kk * 32 + csub) * 2) ^ ((j & 7) << 4)));
      acc2[n] = __builtin_amdgcn_mfma_f32_16x16x32_bf16(av, __builtin_bit_cast(bf16x8, bu), acc2[n], 0, 0, 0);
    }
  }
#pragma unroll
  for (int n = 0; n < 4; n++) {
#pragma unroll
    for (int i = 0; i < 4; i++) {
      int r = wv * 16 + lq * 4 + i, col = n * 16 + l15;
      *(unsigned short*)(s_ah + r * 128 + ((col * 2) ^ ((r & 7) << 4))) = f2bf(acc2[n][i]);
    }
  }
  // ---- dec1 ----
  f32x4 acc3[4];
#pragma unroll
  for (int n = 0; n < 4; n++) {
    float bv = s_bd1[n * 16 + l15];
#pragma unroll
    for (int i = 0; i < 4; i++) acc3[n][i] = bv;
  }
#pragma unroll
  for (int kk = 0; kk < 2; kk++) {
    ushortx8 au = *(const ushortx8*)(s_ah + row_l * 128 + (((kk * 32 + csub) * 2) ^ rsw));
    bf16x8 av = __builtin_bit_cast(bf16x8, au);
#pragma unroll
    for (int n = 0; n < 4; n++) {
      int j = n * 16 + l15;
      ushortx8 bu = *(const ushortx8*)(s_wd1 + j * 128 + (((kk * 32 + csub) * 2) ^ ((j & 7) << 4)));
      acc3[n] = __builtin_amdgcn_mfma_f32_16x16x32_bf16(av, __builtin_bit_cast(bf16x8, bu), acc3[n], 0, 0, 0);
    }
  }
#pragma unroll
  for (int n = 0; n < 4; n++) {
#pragma unroll
    for (int i = 0; i < 4; i++) {
      int r = wv * 16 + lq * 4 + i, col = n * 16 + l15;
      *(unsigned short*)(s_ah + r * 128 + ((col * 2) ^ ((r & 7) << 4))) = f2bf(fmaxf(acc3[n][i], 0.f));
    }
  }
  // ---- dec2 ----
  ushortx8 u0 = *(const ushortx8*)(s_ah + row_l * 128 + ((lq * 32) ^ rsw));
  ushortx8 u1 = *(const ushortx8*)(s_ah + row_l * 128 + ((lq * 32 + 16) ^ rsw));
  float p[3] = {0.f, 0.f, 0.f};
#pragma unroll
  for (int i = 0; i < 8; i++) {
    float x0 = bf2f(u0[i]), x1 = bf2f(u1[i]);
    int c0 = lq * 16 + i, c1 = lq * 16 + 8 + i;
#pragma unroll
    for (int t = 0; t < 3; t++) p[t] += x0 * s_wd2[c0 * 3 + t] + x1 * s_wd2[c1 * 3 + t];
  }
#pragma unroll
  for (int t = 0; t < 3; t++) {
    p[t] += __shfl_xor(p[t], 16);
    p[t] += __shfl_xor(p[t], 32);
  }
  // ---- RK4 bookkeeping ----
  float dt = tspan[s + 1] - tspan[s];
  float o[3];
#pragma unroll
  for (int t = 0; t < 3; t++) o[t] = (p[t] + b_dec2[t]) * astd[t] + amean[t];
  const float ck = (k == 2) ? 1.0f : 0.5f;
  float vs[3] = {0.f, 0.f, 0.f};
  if (noderow < NN) {
    if (lq == 0) {
#pragma unroll
      for (int t = 0; t < 3; t++) {
        float v0v = V0[noderow * 3 + t];
        float wk = (k == 0 || k == 3) ? 1.f : 2.f;
        float va = (k == 0) ? o[t] : vacc[noderow * 3 + t] + wk * o[t];
        if (k < 3) {
          vacc[noderow * 3 + t] = va;
          vs[t] = v0v + ck * dt * o[t];
        } else {
          float vn = v0v + (dt / 6.f) * va;
          vel_next[noderow * 3 + t] = vn;
          vs[t] = vn;
        }
      }
    } else if (lq == 1) {
#pragma unroll
      for (int t = 0; t < 3; t++) {
        if (k < 3) {
          float v0v = V0[noderow * 3 + t];
          float vst = v0v + ck * dt * o[t];
          float pa;
          if (k == 0) pa = v0v + 2.f * vst;
          else pa = pacc[noderow * 3 + t] + ((k == 1) ? 2.f : 1.f) * vst;
          pacc[noderow * 3 + t] = pa;
        } else {
          pos_next[noderow * 3 + t] = pos_prev[noderow * 3 + t] + (dt / 6.f) * pacc[noderow * 3 + t];
        }
      }
    }
  }
  // ---- fused encoder for next stage ----
  if (do_enc) {
    for (int i = 0; i < 16; i++) {
      int rl = wv * 16 + i, node = n0b + rl;
      float v0s = __shfl(vs[0], i);
      float v1s = __shfl(vs[1], i);
      float v2s = __shfl(vs[2], i);
      float hv = 0.f;
      if (node < NN) {
        float vn0 = (v0s - s_vm[0]) / s_vs[0];
        float vn1 = (v1s - s_vm[1]) / s_vs[1];
        float vn2 = (v2s - s_vm[2]) / s_vs[2];
        float a = h_pre[(size_t)node * 64 + lane] + vn0 * s_w1e[lane] + vn1 * s_w1e[64 + lane] + vn2 * s_w1e[128 + lane];
        hv = fmaxf(a, 0.f);
      }
      *(unsigned short*)(s_ah + rl * 128 + ((lane * 2) ^ ((rl & 7) << 4))) = f2bf(hv);
    }
    f32x4 ae[4];
#pragma unroll
    for (int n = 0; n < 4; n++) {
      float bv = s_be2[n * 16 + l15];
#pragma unroll
      for (int i = 0; i < 4; i++) ae[n][i] = bv;
    }
#pragma unroll
    for (int kk = 0; kk < 2; kk++) {
      ushortx8 au = *(const ushortx8*)(s_ah + row_l * 128 + (((kk * 32 + csub) * 2) ^ rsw));
      bf16x8 av = __builtin_bit_cast(bf16x8, au);
#pragma unroll
      for (int n = 0; n < 4; n++) {
        int j = n * 16 + l15;
        ushortx8 bu = *(const ushortx8*)(s_w2e + j * 128 + (((kk * 32 + csub) * 2) ^ ((j & 7) << 4)));
        ae[n] = __builtin_amdgcn_mfma_f32_16x16x32_bf16(av, __builtin_bit_cast(bf16x8, bu), ae[n], 0, 0, 0);
      }
    }
#pragma unroll
    for (int n = 0; n < 4; n++) {
#pragma unroll
      for (int i = 0; i < 4; i++) {
        int r = wv * 16 + lq * 4 + i, rowg = n0b + r, col = n * 16 + l15;
        if (rowg < NN) hbuf[(size_t)rowg * 64 + col] = ae[n][i];
        *(unsigned short*)(s_ah + r * 128 + ((col * 2) ^ ((r & 7) << 4))) = f2bf(ae[n][i]);
      }
    }
    if (noderow < NN) {
      ushortx8 q0 = *(const ushortx8*)(s_ah + row_l * 128 + ((lq * 32) ^ rsw));
      ushortx8 q1 = *(const ushortx8*)(s_ah + row_l * 128 + ((lq * 32 + 16) ^ rsw));
      ushortx8* op = (ushortx8*)(h_bf + (size_t)noderow * 64);
      op[lq * 2] = q0;
      op[lq * 2 + 1] = q1;
    }
  }
}

extern "C" void kernel_launch(void* const* d_in, const int* in_sizes, int n_in,
                              void* d_out, int out_size, void* d_ws, size_t ws_size,
                              hipStream_t stream) {
  (void)in_sizes; (void)n_in; (void)out_size; (void)ws_size;
  const float* world_pos = (const float*)d_in[0];
  const float* velocity  = (const float*)d_in[1];
  const int*   eidx      = (const int*)d_in[2];
  const float* eattr     = (const float*)d_in[3];
  const float* youngs    = (const float*)d_in[4];
  const float* onehot    = (const float*)d_in[5];
  const float* tspan     = (const float*)d_in[7];
  const float* ym        = (const float*)d_in[8];
  const float* ys        = (const float*)d_in[9];
  const float* emean     = (const float*)d_in[10];
  const float* estd      = (const float*)d_in[11];
  const float* vmean     = (const float*)d_in[12];
  const float* vstd      = (const float*)d_in[13];
  const float* amean     = (const float*)d_in[14];
  const float* astd      = (const float*)d_in[15];
  const float* w_ne1 = (const float*)d_in[16]; const float* b_ne1 = (const float*)d_in[17];
  const float* w_ne2 = (const float*)d_in[18]; const float* b_ne2 = (const float*)d_in[19];
  const float* w_ee1 = (const float*)d_in[20]; const float* b_ee1 = (const float*)d_in[21];
  const float* w_ee2 = (const float*)d_in[22]; const float* b_ee2 = (const float*)d_in[23];
  const float* w_em1 = (const float*)d_in[24]; const float* b_em1 = (const float*)d_in[25];
  const float* w_em2 = (const float*)d_in[26]; const float* b_em2 = (const float*)d_in[27];
  const float* w_nm1 = (const float*)d_in[28]; const float* b_nm1 = (const float*)d_in[29];
  const float* w_nm2 = (const float*)d_in[30]; const float* b_nm2 = (const float*)d_in[31];
  const float* w_dec1 = (const float*)d_in[32]; const float* b_dec1 = (const float*)d_in[33];
  const float* w_dec2 = (const float*)d_in[34]; const float* b_dec2 = (const float*)d_in[35];

  char* ws = (char*)d_ws;
  float* h_pre  = (float*)ws; ws += (size_t)NN * HD * 4;
  float* hbuf   = (float*)ws; ws += (size_t)NN * HD * 4;
  char* eenc_sw = ws; ws += (size_t)NE * 128;
  unsigned short* emsg_bf = (unsigned short*)ws; ws += (size_t)NE * HD * 2;
  unsigned short* h_bf    = (unsigned short*)ws; ws += (size_t)NN * HD * 2;
  char* w1em  = ws; ws += 64 * 384;
  char* w2em  = ws; ws += 64 * 128;
  char* wnm1s = ws; ws += 64 * 256;
  char* wnm2s = ws; ws += 64 * 128;
  char* wdec1s = ws; ws += 64 * 128;
  char* wne2s = ws; ws += 64 * 128;
  char* wee2s = ws; ws += 64 * 128;
  float* vacc = (float*)ws; ws += (size_t)NN * 3 * 4;
  float* pacc = (float*)ws; ws += (size_t)NN * 3 * 4;
  int* counts  = (int*)ws; ws += (size_t)NN * 4;
  int* fill    = (int*)ws; ws += (size_t)NN * 4;
  int* slot    = (int*)ws; ws += (size_t)NE * 4;
  int* row_ptr = (int*)ws; ws += (size_t)(NN + 1) * 4;
  int* bsums   = (int*)ws; ws += (size_t)128 * 4;

  float* PO = (float*)d_out;
  float* VO = PO + (size_t)TT * NN * 3;

  // --- once-per-launch precompute ---
  k_prep<<<(NN * HD) / 256, 256, 0, stream>>>(world_pos, velocity, PO, VO, counts, fill,
                                              youngs, onehot, ym, ys, w_ne1, b_ne1, h_pre,
                                              w_em1, w_em2, w_nm1, w_nm2, w_dec1, w_ne2, w_ee2,
                                              w1em, w2em, wnm1s, wnm2s, wdec1s, wne2s, wee2s);
  k_edge_enc_mfma<<<NE / 64, 256, 0, stream>>>(eattr, emean, estd, w_ee1, b_ee1, wee2s, b_ee2, eenc_sw);
  k_count<<<NE / 256, 256, 0, stream>>>(eidx, counts);
  k_scanA<<<SCAN_NB, 256, 0, stream>>>(counts, row_ptr, bsums);
  k_scanB<<<1, 128, 0, stream>>>(bsums);
  k_scanC<<<SCAN_NB, 256, 0, stream>>>(row_ptr, bsums);
  k_place<<<NE / 256, 256, 0, stream>>>(eidx, row_ptr, fill, slot);

  const int NBLK_ENC = (NN + 63) / 64;
  const int NBLK_UPD = (NN + 31) / 32;
  k_enc_mfma<<<NBLK_ENC, 256, 0, stream>>>(velocity, vmean, vstd, w_ne1, h_pre, wne2s, b_ne2, hbuf, h_bf);

  for (int s = 0; s < TT - 1; s++) {
    const float* V0 = VO + (size_t)s * NN * 3;
    const float* pos_prev = PO + (size_t)s * NN * 3;
    float* pos_next = PO + (size_t)(s + 1) * NN * 3;
    float* vel_next = VO + (size_t)(s + 1) * NN * 3;
    for (int k = 0; k < 4; k++) {
      k_edge_mfma<<<EDGE_GRID, 256, 0, stream>>>(eidx, slot, h_bf, eenc_sw, w1em, w2em,
                                                 b_em1, b_em2, emsg_bf);
      int do_enc = !(s == TT - 2 && k == 3);
      k_upd_enc<<<NBLK_UPD, 128, 0, stream>>>(row_ptr, emsg_bf, hbuf, h_bf,
                                              wnm1s, wnm2s, wdec1s, wne2s,
                                              b_nm1, b_nm2, b_dec1, b_dec2, w_dec2, amean, astd,
                                              w_ne1, h_pre, b_ne2, vmean, vstd,
                                              tspan, s, k, do_enc,
                                              V0, vacc, pacc, pos_prev, pos_next, vel_next);
    }
  }
}

// Round 10
// 414.280 us; speedup vs baseline: 1.9016x; 1.0199x over previous
//
#include <hip/hip_runtime.h>
#include <hip/hip_bf16.h>

#define NN 20000
#define NE 160000
#define HD 64
#define TT 3

typedef unsigned short ushortx8 __attribute__((ext_vector_type(8)));
typedef float f32x4 __attribute__((ext_vector_type(4)));
typedef __bf16 bf16x8 __attribute__((ext_vector_type(8)));

__device__ __forceinline__ unsigned short f2bf(float f) {
  unsigned int x = __float_as_uint(f);
  unsigned int r = (x + 0x7fffu + ((x >> 16) & 1u)) >> 16;  // RNE, finite inputs
  return (unsigned short)r;
}
__device__ __forceinline__ float bf2f(unsigned short u) {
  return __uint_as_float(((unsigned int)u) << 16);
}

// ---------------- fused precompute: init out, zero counts, h_pre, weight prep ----------------
__global__ __launch_bounds__(256) void k_prep(const float* __restrict__ wp,
    const float* __restrict__ vel, float* __restrict__ PO, float* __restrict__ VO,
    int* __restrict__ counts, int* __restrict__ fill,
    const float* __restrict__ youngs, const float* __restrict__ onehot,
    const float* __restrict__ ym, const float* __restrict__ ys,
    const float* __restrict__ w_ne1, const float* __restrict__ b_ne1, float* __restrict__ h_pre,
    const float* __restrict__ w_em1, const float* __restrict__ w_em2,
    const float* __restrict__ w_nm1, const float* __restrict__ w_nm2,
    const float* __restrict__ w_dec1, const float* __restrict__ w_ne2, const float* __restrict__ w_ee2,
    char* __restrict__ w1em, char* __restrict__ w2em, char* __restrict__ wnm1,
    char* __restrict__ wnm2, char* __restrict__ wdec1, char* __restrict__ wne2,
    char* __restrict__ wee2) {
  int idx = blockIdx.x * 256 + threadIdx.x;
  if (idx < NN * 3) { PO[idx] = wp[idx]; VO[idx] = vel[idx]; }
  if (idx < NN) { counts[idx] = 0; fill[idx] = 0; }
  {  // h_pre (all idx < NN*HD; grid == NN*HD/256)
    int n = idx >> 6, j = idx & 63;
    float a = b_ne1[j];
    float yn = (youngs[n] - ym[0]) / ys[0];
    a += yn * w_ne1[3 * HD + j];
#pragma unroll
    for (int k = 0; k < 9; k++) a += onehot[n * 9 + k] * w_ne1[(4 + k) * HD + j];
    h_pre[idx] = a;
  }
  int w = idx;
  if (w < 12288) {
    int j = w / 192, k = w % 192;
    *(unsigned short*)(w1em + j * 384 + ((k * 2) ^ ((j & 7) << 4))) = f2bf(w_em1[k * 64 + j]);
    return;
  }
  w -= 12288;
  if (w < 4096) {
    int j = w >> 6, k = w & 63;
    *(unsigned short*)(w2em + j * 128 + ((k * 2) ^ ((j & 7) << 4))) = f2bf(w_em2[k * 64 + j]);
    return;
  }
  w -= 4096;
  if (w < 8192) {
    int j = w >> 7, k = w & 127;
    *(unsigned short*)(wnm1 + j * 256 + ((k * 2) ^ ((j & 7) << 4))) = f2bf(w_nm1[k * 64 + j]);
    return;
  }
  w -= 8192;
  if (w < 4096) {
    int j = w >> 6, k = w & 63;
    *(unsigned short*)(wnm2 + j * 128 + ((k * 2) ^ ((j & 7) << 4))) = f2bf(w_nm2[k * 64 + j]);
    return;
  }
  w -= 4096;
  if (w < 4096) {
    int j = w >> 6, k = w & 63;
    *(unsigned short*)(wdec1 + j * 128 + ((k * 2) ^ ((j & 7) << 4))) = f2bf(w_dec1[k * 64 + j]);
    return;
  }
  w -= 4096;
  if (w < 4096) {
    int j = w >> 6, k = w & 63;
    *(unsigned short*)(wne2 + j * 128 + ((k * 2) ^ ((j & 7) << 4))) = f2bf(w_ne2[k * 64 + j]);
    return;
  }
  w -= 4096;
  if (w < 4096) {
    int j = w >> 6, k = w & 63;
    *(unsigned short*)(wee2 + j * 128 + ((k * 2) ^ ((j & 7) << 4))) = f2bf(w_ee2[k * 64 + j]);
    return;
  }
}

// ---------------- static edge encoder via MFMA (once) -> pre-swizzled bf16 (+ dst count) ----------------
__global__ __launch_bounds__(256) void k_edge_enc_mfma(const float* __restrict__ eattr,
    const float* __restrict__ emean, const float* __restrict__ estd,
    const float* __restrict__ w_ee1, const float* __restrict__ b_ee1,
    const char* __restrict__ wee2sw, const float* __restrict__ b_ee2,
    char* __restrict__ eenc_sw, const int* __restrict__ eidx, int* __restrict__ counts) {
  __shared__ __align__(16) char s_w2[64 * 128];
  __shared__ __align__(16) char s_hid[64 * 128];
  __shared__ float s_w1[4 * 64], s_b1[64], s_b2[64], s_m[4], s_s[4];
  int tid = threadIdx.x, e0b = blockIdx.x * 64;
  for (int c = tid; c < 512; c += 256) ((ushortx8*)s_w2)[c] = ((const ushortx8*)wee2sw)[c];
  if (tid < 256) s_w1[tid] = w_ee1[tid];
  if (tid < 64) { s_b1[tid] = b_ee1[tid]; s_b2[tid] = b_ee2[tid]; }
  if (tid < 4) { s_m[tid] = emean[tid]; s_s[tid] = estd[tid]; }
  __syncthreads();
  int lane = tid & 63, wv = tid >> 6, l15 = lane & 15, lq = lane >> 4, csub = lq * 8;
  int row_l = wv * 16 + l15, rsw = (l15 & 7) << 4;
  int erow = e0b + row_l;
  if (lq == 0) atomicAdd(&counts[eidx[NE + erow]], 1);  // fused k_count
  float4 at = ((const float4*)eattr)[erow];
  float x0 = (at.x - s_m[0]) / s_s[0];
  float x1 = (at.y - s_m[1]) / s_s[1];
  float x2 = (at.z - s_m[2]) / s_s[2];
  float x3 = (at.w - s_m[3]) / s_s[3];
#pragma unroll 4
  for (int i = 0; i < 16; i++) {
    int rl = wv * 16 + i;
    float y0 = __shfl(x0, i), y1 = __shfl(x1, i), y2 = __shfl(x2, i), y3 = __shfl(x3, i);
    float a = s_b1[lane] + y0 * s_w1[lane] + y1 * s_w1[64 + lane] + y2 * s_w1[128 + lane] + y3 * s_w1[192 + lane];
    *(unsigned short*)(s_hid + rl * 128 + ((lane * 2) ^ ((rl & 7) << 4))) = f2bf(fmaxf(a, 0.f));
  }
  f32x4 acc[4];
#pragma unroll
  for (int n = 0; n < 4; n++) {
    float bv = s_b2[n * 16 + l15];
#pragma unroll
    for (int i = 0; i < 4; i++) acc[n][i] = bv;
  }
#pragma unroll
  for (int kk = 0; kk < 2; kk++) {
    ushortx8 au = *(const ushortx8*)(s_hid + row_l * 128 + (((kk * 32 + csub) * 2) ^ rsw));
    bf16x8 av = __builtin_bit_cast(bf16x8, au);
#pragma unroll
    for (int n = 0; n < 4; n++) {
      int j = n * 16 + l15;
      ushortx8 bu = *(const ushortx8*)(s_w2 + j * 128 + (((kk * 32 + csub) * 2) ^ ((j & 7) << 4)));
      acc[n] = __builtin_amdgcn_mfma_f32_16x16x32_bf16(av, __builtin_bit_cast(bf16x8, bu), acc[n], 0, 0, 0);
    }
  }
#pragma unroll
  for (int n = 0; n < 4; n++) {
#pragma unroll
    for (int i = 0; i < 4; i++) {
      int r = wv * 16 + lq * 4 + i, col = n * 16 + l15;
      *(unsigned short*)(s_hid + r * 128 + ((col * 2) ^ ((r & 7) << 4))) = f2bf(acc[n][i]);
    }
  }
  ushortx8 q0 = *(const ushortx8*)(s_hid + row_l * 128 + lq * 32);
  ushortx8 q1 = *(const ushortx8*)(s_hid + row_l * 128 + lq * 32 + 16);
  *(ushortx8*)(eenc_sw + (size_t)erow * 128 + lq * 32) = q0;
  *(ushortx8*)(eenc_sw + (size_t)erow * 128 + lq * 32 + 16) = q1;
}

// ---------------- CSR build ----------------
#define SCAN_NB ((NN + 255) / 256)
__global__ __launch_bounds__(256) void k_scanA(const int* __restrict__ counts,
    int* __restrict__ row_ptr, int* __restrict__ bsums) {
  __shared__ int tmp[256];
  int tid = threadIdx.x;
  int g = blockIdx.x * 256 + tid;
  int v = (g < NN) ? counts[g] : 0;
  tmp[tid] = v;
  __syncthreads();
#pragma unroll
  for (int off = 1; off < 256; off <<= 1) {
    int t = (tid >= off) ? tmp[tid - off] : 0;
    __syncthreads();
    tmp[tid] += t;
    __syncthreads();
  }
  if (g < NN) row_ptr[g] = tmp[tid] - v;
  if (tid == 255) bsums[blockIdx.x] = tmp[255];
}

__global__ __launch_bounds__(128) void k_scanB(int* __restrict__ bsums) {
  __shared__ int tmp[128];
  int tid = threadIdx.x;
  int v = (tid < SCAN_NB) ? bsums[tid] : 0;
  tmp[tid] = v;
  __syncthreads();
#pragma unroll
  for (int off = 1; off < 128; off <<= 1) {
    int t = (tid >= off) ? tmp[tid - off] : 0;
    __syncthreads();
    tmp[tid] += t;
    __syncthreads();
  }
  if (tid < SCAN_NB) bsums[tid] = tmp[tid] - v;
}

__global__ __launch_bounds__(256) void k_scanC(int* __restrict__ row_ptr, const int* __restrict__ bsums) {
  int g = blockIdx.x * 256 + threadIdx.x;
  if (g < NN) row_ptr[g] += bsums[blockIdx.x];
  if (g == 0) row_ptr[NN] = NE;
}

__global__ __launch_bounds__(256) void k_place(const int* __restrict__ eidx,
    const int* __restrict__ row_ptr, int* __restrict__ fill, int* __restrict__ slot) {
  int e = blockIdx.x * 256 + threadIdx.x;
  if (e >= NE) return;
  int d = eidx[NE + e];
  int f = atomicAdd(&fill[d], 1);
  slot[e] = row_ptr[d] + f;
}

// ---------------- initial node encoder (t=0 only) ----------------
__global__ __launch_bounds__(256) void k_enc_mfma(const float* __restrict__ vel,
    const float* __restrict__ vmean, const float* __restrict__ vstd,
    const float* __restrict__ w_ne1, const float* __restrict__ h_pre,
    const char* __restrict__ wne2sw, const float* __restrict__ b_ne2,
    float* __restrict__ h, unsigned short* __restrict__ h_bf) {
  __shared__ __align__(16) char s_w2[64 * 128];
  __shared__ __align__(16) char s_hid[64 * 128];
  __shared__ float s_w1[3 * 64], s_b2[64], s_vm[3], s_vs[3];
  int tid = threadIdx.x, n0b = blockIdx.x * 64;
  for (int c = tid; c < 512; c += 256) ((ushortx8*)s_w2)[c] = ((const ushortx8*)wne2sw)[c];
  if (tid < 192) s_w1[tid] = w_ne1[tid];
  if (tid < 64) s_b2[tid] = b_ne2[tid];
  if (tid < 3) { s_vm[tid] = vmean[tid]; s_vs[tid] = vstd[tid]; }
  __syncthreads();
  int lane = tid & 63, wv = tid >> 6, l15 = lane & 15, lq = lane >> 4, csub = lq * 8;
#pragma unroll 4
  for (int i = 0; i < 16; i++) {
    int rl = wv * 16 + i, node = n0b + rl;
    float hv = 0.f;
    if (node < NN) {
      float v0 = (vel[node * 3 + 0] - s_vm[0]) / s_vs[0];
      float v1 = (vel[node * 3 + 1] - s_vm[1]) / s_vs[1];
      float v2 = (vel[node * 3 + 2] - s_vm[2]) / s_vs[2];
      float a = h_pre[(size_t)node * 64 + lane] + v0 * s_w1[lane] + v1 * s_w1[64 + lane] + v2 * s_w1[128 + lane];
      hv = fmaxf(a, 0.f);
    }
    *(unsigned short*)(s_hid + rl * 128 + ((lane * 2) ^ ((rl & 7) << 4))) = f2bf(hv);
  }
  int row_l = wv * 16 + l15, rsw = (l15 & 7) << 4;
  f32x4 acc[4];
#pragma unroll
  for (int n = 0; n < 4; n++) {
    float bv = s_b2[n * 16 + l15];
#pragma unroll
    for (int i = 0; i < 4; i++) acc[n][i] = bv;
  }
#pragma unroll
  for (int kk = 0; kk < 2; kk++) {
    ushortx8 au = *(const ushortx8*)(s_hid + row_l * 128 + (((kk * 32 + csub) * 2) ^ rsw));
    bf16x8 av = __builtin_bit_cast(bf16x8, au);
#pragma unroll
    for (int n = 0; n < 4; n++) {
      int j = n * 16 + l15;
      ushortx8 bu = *(const ushortx8*)(s_w2 + j * 128 + (((kk * 32 + csub) * 2) ^ ((j & 7) << 4)));
      acc[n] = __builtin_amdgcn_mfma_f32_16x16x32_bf16(av, __builtin_bit_cast(bf16x8, bu), acc[n], 0, 0, 0);
    }
  }
#pragma unroll
  for (int n = 0; n < 4; n++) {
#pragma unroll
    for (int i = 0; i < 4; i++) {
      int r = wv * 16 + lq * 4 + i, rowg = n0b + r, col = n * 16 + l15;
      if (rowg < NN) h[(size_t)rowg * 64 + col] = acc[n][i];
      *(unsigned short*)(s_hid + r * 128 + ((col * 2) ^ ((r & 7) << 4))) = f2bf(acc[n][i]);
    }
  }
  int noderow = n0b + row_l;
  if (noderow < NN) {
    ushortx8 q0 = *(const ushortx8*)(s_hid + row_l * 128 + ((lq * 32) ^ rsw));
    ushortx8 q1 = *(const ushortx8*)(s_hid + row_l * 128 + ((lq * 32 + 16) ^ rsw));
    ushortx8* op = (ushortx8*)(h_bf + (size_t)noderow * 64);
    op[lq * 2] = q0;
    op[lq * 2 + 1] = q1;
  }
}

// ---------------- per-deriv: edge message MLP via MFMA, persistent + staged eenc ----------------
// R7 lockstep structure + FULL next-tile prefetch: eenc AND eidx/slot/h gathers for
// tile t+1 issue right after barrier #2, hiding under tile t's entire compute.
#define EDGE_GRID 1024
__global__ __launch_bounds__(256, 4) void k_edge_mfma(
    const int* __restrict__ eidx, const int* __restrict__ slot,
    const unsigned short* __restrict__ h_bf, const char* __restrict__ eenc_sw,
    const char* __restrict__ w1sw, const char* __restrict__ w2sw,
    const float* __restrict__ b_em1, const float* __restrict__ b_em2,
    unsigned short* __restrict__ emsg) {
  __shared__ __align__(16) char s_w1[64 * 384];  // 24KB
  __shared__ __align__(16) char s_w2[64 * 128];  // 8KB
  __shared__ __align__(16) char s_eh[64 * 128];  // 8KB: ee tile / hid / out overlay
  int tid = threadIdx.x;
  int lane = tid & 63, wv = tid >> 6, l15 = lane & 15, lq = lane >> 4, csub = lq * 8;
  int erow_loc = wv * 16 + l15;
  int rsw = (l15 & 7) << 4;
  for (int c = tid; c < 1536; c += 256) ((ushortx8*)s_w1)[c] = ((const ushortx8*)w1sw)[c];
  for (int c = tid; c < 512; c += 256) ((ushortx8*)s_w2)[c] = ((const ushortx8*)w2sw)[c];
  float bv1[4], bv2[4];
#pragma unroll
  for (int n = 0; n < 4; n++) { bv1[n] = b_em1[n * 16 + l15]; bv2[n] = b_em2[n * 16 + l15]; }

  const int NT = NE / 64;
  // prologue: prefetch everything for tile t0
  int t = blockIdx.x;
  ushortx8 stg0, stg1, a2, a3, a4, a5;
  int sl;
  {
    const ushortx8* src = (const ushortx8*)(eenc_sw + (size_t)t * 64 * 128);
    stg0 = src[tid];
    stg1 = src[tid + 256];
    int eg = t * 64 + erow_loc;
    int sidx = eidx[eg], didx = eidx[NE + eg];
    sl = slot[eg];
    const ushortx8* hs = (const ushortx8*)(h_bf + (size_t)sidx * HD);
    const ushortx8* hd = (const ushortx8*)(h_bf + (size_t)didx * HD);
    a2 = hs[lq]; a3 = hs[4 + lq]; a4 = hd[lq]; a5 = hd[4 + lq];
  }
  while (t < NT) {
    __syncthreads();  // prev tile done with s_eh (1st iter: weights visible)
    ((ushortx8*)s_eh)[tid] = stg0;
    ((ushortx8*)s_eh)[tid + 256] = stg1;
    __syncthreads();  // s_eh ready
    // issue ALL of next tile's loads now; they complete under this tile's compute
    int tn = t + EDGE_GRID;
    ushortx8 stg0n, stg1n, a2n, a3n, a4n, a5n;
    int sln = 0;
    if (tn < NT) {
      const ushortx8* srcn = (const ushortx8*)(eenc_sw + (size_t)tn * 64 * 128);
      stg0n = srcn[tid];
      stg1n = srcn[tid + 256];
      int egn = tn * 64 + erow_loc;
      int sidxn = eidx[egn], didxn = eidx[NE + egn];
      sln = slot[egn];
      const ushortx8* hsn = (const ushortx8*)(h_bf + (size_t)sidxn * HD);
      const ushortx8* hdn = (const ushortx8*)(h_bf + (size_t)didxn * HD);
      a2n = hsn[lq]; a3n = hsn[4 + lq]; a4n = hdn[lq]; a5n = hdn[4 + lq];
    } else {
      stg0n = stg0; stg1n = stg1; a2n = a2; a3n = a3; a4n = a4; a5n = a5;
    }
    ushortx8 a0 = *(const ushortx8*)(s_eh + erow_loc * 128 + ((csub * 2) ^ rsw));
    ushortx8 a1 = *(const ushortx8*)(s_eh + erow_loc * 128 + ((64 + csub * 2) ^ rsw));
    f32x4 acc[4];
#pragma unroll
    for (int n = 0; n < 4; n++) {
#pragma unroll
      for (int i = 0; i < 4; i++) acc[n][i] = bv1[n];
    }
    ushortx8 af[6] = {a0, a1, a2, a3, a4, a5};
#pragma unroll
    for (int kk = 0; kk < 6; kk++) {
      bf16x8 av = __builtin_bit_cast(bf16x8, af[kk]);
#pragma unroll
      for (int n = 0; n < 4; n++) {
        int j = n * 16 + l15;
        ushortx8 bu = *(const ushortx8*)(s_w1 + j * 384 + (((kk * 32 + csub) * 2) ^ ((j & 7) << 4)));
        acc[n] = __builtin_amdgcn_mfma_f32_16x16x32_bf16(av, __builtin_bit_cast(bf16x8, bu), acc[n], 0, 0, 0);
      }
    }
    // residual C-init from s_eh (ee) BEFORE overwriting with hid (own-wave rows only)
    f32x4 acc2[4];
#pragma unroll
    for (int n = 0; n < 4; n++) {
#pragma unroll
      for (int i = 0; i < 4; i++) {
        int r = wv * 16 + lq * 4 + i, col = n * 16 + l15;
        unsigned short ev = *(const unsigned short*)(s_eh + r * 128 + ((col * 2) ^ ((r & 7) << 4)));
        acc2[n][i] = bv2[n] + bf2f(ev);
      }
    }
    // relu(acc) -> hid into own-wave rows
#pragma unroll
    for (int n = 0; n < 4; n++) {
#pragma unroll
      for (int i = 0; i < 4; i++) {
        int r = wv * 16 + lq * 4 + i, col = n * 16 + l15;
        *(unsigned short*)(s_eh + r * 128 + ((col * 2) ^ ((r & 7) << 4))) = f2bf(fmaxf(acc[n][i], 0.f));
      }
    }
#pragma unroll
    for (int kk = 0; kk < 2; kk++) {
      ushortx8 au = *(const ushortx8*)(s_eh + erow_loc * 128 + (((kk * 32 + csub) * 2) ^ rsw));
      bf16x8 av = __builtin_bit_cast(bf16x8, au);
#pragma unroll
      for (int n = 0; n < 4; n++) {
        int j = n * 16 + l15;
        ushortx8 bu = *(const ushortx8*)(s_w2 + j * 128 + (((kk * 32 + csub) * 2) ^ ((j & 7) << 4)));
        acc2[n] = __builtin_amdgcn_mfma_f32_16x16x32_bf16(av, __builtin_bit_cast(bf16x8, bu), acc2[n], 0, 0, 0);
      }
    }
#pragma unroll
    for (int n = 0; n < 4; n++) {
#pragma unroll
      for (int i = 0; i < 4; i++) {
        int r = wv * 16 + lq * 4 + i, col = n * 16 + l15;
        *(unsigned short*)(s_eh + r * 128 + ((col * 2) ^ ((r & 7) << 4))) = f2bf(acc2[n][i]);
      }
    }
    ushortx8 q0 = *(const ushortx8*)(s_eh + erow_loc * 128 + ((lq * 32) ^ rsw));
    ushortx8 q1 = *(const ushortx8*)(s_eh + erow_loc * 128 + ((lq * 32 + 16) ^ rsw));
    ushortx8* op = (ushortx8*)(emsg + (size_t)sl * HD);
    op[lq * 2] = q0;
    op[lq * 2 + 1] = q1;
    // rotate pipeline
    t = tn;
    stg0 = stg0n; stg1 = stg1n;
    a2 = a2n; a3 = a3n; a4 = a4n; a5 = a5n;
    sl = sln;
  }
}

// ---------------- per-deriv: agg + node MLP + decoder + RK4 accum + NEXT encoder ----------------
// R7-proven 256-thread / 4-wave / 64-node version.
__global__ __launch_bounds__(256) void k_upd_enc(
    const int* __restrict__ row_ptr, const unsigned short* __restrict__ emsg,
    float* __restrict__ hbuf, unsigned short* __restrict__ h_bf,
    const char* __restrict__ wnm1sw, const char* __restrict__ wnm2sw,
    const char* __restrict__ wdec1sw, const char* __restrict__ wne2sw,
    const float* __restrict__ b_nm1, const float* __restrict__ b_nm2,
    const float* __restrict__ b_dec1, const float* __restrict__ b_dec2,
    const float* __restrict__ w_dec2, const float* __restrict__ amean, const float* __restrict__ astd,
    const float* __restrict__ w_ne1, const float* __restrict__ h_pre,
    const float* __restrict__ b_ne2, const float* __restrict__ vmean, const float* __restrict__ vstd,
    const float* __restrict__ tspan, int s, int k, int do_enc,
    const float* __restrict__ V0, float* __restrict__ vacc, float* __restrict__ pacc,
    const float* __restrict__ pos_prev, float* __restrict__ pos_next, float* __restrict__ vel_next) {
  __shared__ __align__(16) char s_w1[64 * 256];
  __shared__ __align__(16) char s_w2[64 * 128];
  __shared__ __align__(16) char s_wd1[64 * 128];
  __shared__ __align__(16) char s_w2e[64 * 128];
  __shared__ __align__(16) char s_ah[64 * 128];
  __shared__ float s_b1[64], s_b2[64], s_bd1[64], s_be2[64], s_wd2[192], s_w1e[192];
  __shared__ float s_vm[3], s_vs[3];
  int tid = threadIdx.x, n0b = blockIdx.x * 64;
  for (int c = tid; c < 1024; c += 256) ((ushortx8*)s_w1)[c] = ((const ushortx8*)wnm1sw)[c];
  for (int c = tid; c < 512; c += 256) ((ushortx8*)s_w2)[c] = ((const ushortx8*)wnm2sw)[c];
  for (int c = tid; c < 512; c += 256) ((ushortx8*)s_wd1)[c] = ((const ushortx8*)wdec1sw)[c];
  for (int c = tid; c < 512; c += 256) ((ushortx8*)s_w2e)[c] = ((const ushortx8*)wne2sw)[c];
  if (tid < 64) { s_b1[tid] = b_nm1[tid]; s_b2[tid] = b_nm2[tid]; s_bd1[tid] = b_dec1[tid]; s_be2[tid] = b_ne2[tid]; }
  if (tid < 192) { s_wd2[tid] = w_dec2[tid]; s_w1e[tid] = w_ne1[tid]; }
  if (tid < 3) { s_vm[tid] = vmean[tid]; s_vs[tid] = vstd[tid]; }

  int lane = tid & 63, wv = tid >> 6, l15 = lane & 15, lq = lane >> 4, csub = lq * 8;
  int row_l = wv * 16 + l15, rsw = (l15 & 7) << 4;
  int noderow = n0b + row_l;
  int ncl = noderow < NN ? noderow : NN - 1;
  ushortx8 afh0 = *(const ushortx8*)(h_bf + (size_t)ncl * 64 + csub);
  ushortx8 afh1 = *(const ushortx8*)(h_bf + (size_t)ncl * 64 + 32 + csub);

  // ---- agg: lane = (row in 0..7, ch-group in 0..7), 2 passes, no shuffles ----
  int arow = lane >> 3, ag = lane & 7;
#pragma unroll
  for (int p = 0; p < 2; p++) {
    int rl = wv * 16 + p * 8 + arow, node = n0b + rl;
    float sm[8] = {0.f, 0.f, 0.f, 0.f, 0.f, 0.f, 0.f, 0.f};
    if (node < NN) {
      int b = row_ptr[node], e = row_ptr[node + 1];
      for (int r = b; r < e; r++) {
        ushortx8 u = *(const ushortx8*)(emsg + (size_t)r * HD + ag * 8);
#pragma unroll
        for (int j = 0; j < 8; j++) sm[j] += bf2f(u[j]);
      }
    }
    ushortx8 u;
#pragma unroll
    for (int j = 0; j < 8; j++) u[j] = f2bf(sm[j]);
    *(ushortx8*)(s_ah + rl * 128 + ((ag * 16) ^ ((rl & 7) << 4))) = u;
  }
  __syncthreads();

  // ---- GEMM1: [h | agg] x wnm1 ----
  f32x4 acc[4];
#pragma unroll
  for (int n = 0; n < 4; n++) {
    float bv = s_b1[n * 16 + l15];
#pragma unroll
    for (int i = 0; i < 4; i++) acc[n][i] = bv;
  }
  ushortx8 af[4];
  af[0] = afh0; af[1] = afh1;
  af[2] = *(const ushortx8*)(s_ah + row_l * 128 + ((csub * 2) ^ rsw));
  af[3] = *(const ushortx8*)(s_ah + row_l * 128 + (((32 + csub) * 2) ^ rsw));
#pragma unroll
  for (int kk = 0; kk < 4; kk++) {
    bf16x8 av = __builtin_bit_cast(bf16x8, af[kk]);
#pragma unroll
    for (int n = 0; n < 4; n++) {
      int j = n * 16 + l15;
      ushortx8 bu = *(const ushortx8*)(s_w1 + j * 256 + (((kk * 32 + csub) * 2) ^ ((j & 7) << 4)));
      acc[n] = __builtin_amdgcn_mfma_f32_16x16x32_bf16(av, __builtin_bit_cast(bf16x8, bu), acc[n], 0, 0, 0);
    }
  }
#pragma unroll
  for (int n = 0; n < 4; n++) {
#pragma unroll
    for (int i = 0; i < 4; i++) {
      int r = wv * 16 + lq * 4 + i, col = n * 16 + l15;
      *(unsigned short*)(s_ah + r * 128 + ((col * 2) ^ ((r & 7) << 4))) = f2bf(fmaxf(acc[n][i], 0.f));
    }
  }
  // ---- GEMM2: hu = h(resid fp32) + b2 + hid x wnm2 ----
  f32x4 acc2[4];
#pragma unroll
  for (int n = 0; n < 4; n++) {
#pragma unroll
    for (int i = 0; i < 4; i++) {
      int r = wv * 16 + lq * 4 + i, col = n * 16 + l15;
      int rg = n0b + r; int rgc = rg < NN ? rg : NN - 1;
      acc2[n][i] = s_b2[col] + hbuf[(size_t)rgc * 64 + col];
    }
  }
#pragma unroll
  for (int kk = 0; kk < 2; kk++) {
    ushortx8 au = *(const ushortx8*)(s_ah + row_l * 128 + (((kk * 32 + csub) * 2) ^ rsw));
    bf16x8 av = __builtin_bit_cast(bf16x8, au);
#pragma unroll
    for (int n = 0; n < 4; n++) {
      int j = n * 16 + l15;
      ushortx8 bu = *(const ushortx8*)(s_w2 + j * 128 + (((kk * 32 + csub) * 2) ^ ((j & 7) << 4)));
      acc2[n] = __builtin_amdgcn_mfma_f32_16x16x32_bf16(av, __builtin_bit_cast(bf16x8, bu), acc2[n], 0, 0, 0);
    }
  }
#pragma unroll
  for (int n = 0; n < 4; n++) {
#pragma unroll
    for (int i = 0; i < 4; i++) {
      int r = wv * 16 + lq * 4 + i, col = n * 16 + l15;
      *(unsigned short*)(s_ah + r * 128 + ((col * 2) ^ ((r & 7) << 4))) = f2bf(acc2[n][i]);
    }
  }
  // ---- dec1 ----
  f32x4 acc3[4];
#pragma unroll
  for (int n = 0; n < 4; n++) {
    float bv = s_bd1[n * 16 + l15];
#pragma unroll
    for (int i = 0; i < 4; i++) acc3[n][i] = bv;
  }
#pragma unroll
  for (int kk = 0; kk < 2; kk++) {
    ushortx8 au = *(const ushortx8*)(s_ah + row_l * 128 + (((kk * 32 + csub) * 2) ^ rsw));
    bf16x8 av = __builtin_bit_cast(bf16x8, au);
#pragma unroll
    for (int n = 0; n < 4; n++) {
      int j = n * 16 + l15;
      ushortx8 bu = *(const ushortx8*)(s_wd1 + j * 128 + (((kk * 32 + csub) * 2) ^ ((j & 7) << 4)));
      acc3[n] = __builtin_amdgcn_mfma_f32_16x16x32_bf16(av, __builtin_bit_cast(bf16x8, bu), acc3[n], 0, 0, 0);
    }
  }
#pragma unroll
  for (int n = 0; n < 4; n++) {
#pragma unroll
    for (int i = 0; i < 4; i++) {
      int r = wv * 16 + lq * 4 + i, col = n * 16 + l15;
      *(unsigned short*)(s_ah + r * 128 + ((col * 2) ^ ((r & 7) << 4))) = f2bf(fmaxf(acc3[n][i], 0.f));
    }
  }
  // ---- dec2 ----
  ushortx8 u0 = *(const ushortx8*)(s_ah + row_l * 128 + ((lq * 32) ^ rsw));
  ushortx8 u1 = *(const ushortx8*)(s_ah + row_l * 128 + ((lq * 32 + 16) ^ rsw));
  float p[3] = {0.f, 0.f, 0.f};
#pragma unroll
  for (int i = 0; i < 8; i++) {
    float x0 = bf2f(u0[i]), x1 = bf2f(u1[i]);
    int c0 = lq * 16 + i, c1 = lq * 16 + 8 + i;
#pragma unroll
    for (int t = 0; t < 3; t++) p[t] += x0 * s_wd2[c0 * 3 + t] + x1 * s_wd2[c1 * 3 + t];
  }
#pragma unroll
  for (int t = 0; t < 3; t++) {
    p[t] += __shfl_xor(p[t], 16);
    p[t] += __shfl_xor(p[t], 32);
  }
  // ---- RK4 bookkeeping ----
  float dt = tspan[s + 1] - tspan[s];
  float o[3];
#pragma unroll
  for (int t = 0; t < 3; t++) o[t] = (p[t] + b_dec2[t]) * astd[t] + amean[t];
  const float ck = (k == 2) ? 1.0f : 0.5f;
  float vs[3] = {0.f, 0.f, 0.f};
  if (noderow < NN) {
    if (lq == 0) {
#pragma unroll
      for (int t = 0; t < 3; t++) {
        float v0v = V0[noderow * 3 + t];
        float wk = (k == 0 || k == 3) ? 1.f : 2.f;
        float va = (k == 0) ? o[t] : vacc[noderow * 3 + t] + wk * o[t];
        if (k < 3) {
          vacc[noderow * 3 + t] = va;
          vs[t] = v0v + ck * dt * o[t];
        } else {
          float vn = v0v + (dt / 6.f) * va;
          vel_next[noderow * 3 + t] = vn;
          vs[t] = vn;
        }
      }
    } else if (lq == 1) {
#pragma unroll
      for (int t = 0; t < 3; t++) {
        if (k < 3) {
          float v0v = V0[noderow * 3 + t];
          float vst = v0v + ck * dt * o[t];
          float pa;
          if (k == 0) pa = v0v + 2.f * vst;
          else pa = pacc[noderow * 3 + t] + ((k == 1) ? 2.f : 1.f) * vst;
          pacc[noderow * 3 + t] = pa;
        } else {
          pos_next[noderow * 3 + t] = pos_prev[noderow * 3 + t] + (dt / 6.f) * pacc[noderow * 3 + t];
        }
      }
    }
  }
  // ---- fused encoder for next stage ----
  if (do_enc) {
    for (int i = 0; i < 16; i++) {
      int rl = wv * 16 + i, node = n0b + rl;
      float v0s = __shfl(vs[0], i);
      float v1s = __shfl(vs[1], i);
      float v2s = __shfl(vs[2], i);
      float hv = 0.f;
      if (node < NN) {
        float vn0 = (v0s - s_vm[0]) / s_vs[0];
        float vn1 = (v1s - s_vm[1]) / s_vs[1];
        float vn2 = (v2s - s_vm[2]) / s_vs[2];
        float a = h_pre[(size_t)node * 64 + lane] + vn0 * s_w1e[lane] + vn1 * s_w1e[64 + lane] + vn2 * s_w1e[128 + lane];
        hv = fmaxf(a, 0.f);
      }
      *(unsigned short*)(s_ah + rl * 128 + ((lane * 2) ^ ((rl & 7) << 4))) = f2bf(hv);
    }
    f32x4 ae[4];
#pragma unroll
    for (int n = 0; n < 4; n++) {
      float bv = s_be2[n * 16 + l15];
#pragma unroll
      for (int i = 0; i < 4; i++) ae[n][i] = bv;
    }
#pragma unroll
    for (int kk = 0; kk < 2; kk++) {
      ushortx8 au = *(const ushortx8*)(s_ah + row_l * 128 + (((kk * 32 + csub) * 2) ^ rsw));
      bf16x8 av = __builtin_bit_cast(bf16x8, au);
#pragma unroll
      for (int n = 0; n < 4; n++) {
        int j = n * 16 + l15;
        ushortx8 bu = *(const ushortx8*)(s_w2e + j * 128 + (((kk * 32 + csub) * 2) ^ ((j & 7) << 4)));
        ae[n] = __builtin_amdgcn_mfma_f32_16x16x32_bf16(av, __builtin_bit_cast(bf16x8, bu), ae[n], 0, 0, 0);
      }
    }
#pragma unroll
    for (int n = 0; n < 4; n++) {
#pragma unroll
      for (int i = 0; i < 4; i++) {
        int r = wv * 16 + lq * 4 + i, rowg = n0b + r, col = n * 16 + l15;
        if (rowg < NN) hbuf[(size_t)rowg * 64 + col] = ae[n][i];
        *(unsigned short*)(s_ah + r * 128 + ((col * 2) ^ ((r & 7) << 4))) = f2bf(ae[n][i]);
      }
    }
    if (noderow < NN) {
      ushortx8 q0 = *(const ushortx8*)(s_ah + row_l * 128 + ((lq * 32) ^ rsw));
      ushortx8 q1 = *(const ushortx8*)(s_ah + row_l * 128 + ((lq * 32 + 16) ^ rsw));
      ushortx8* op = (ushortx8*)(h_bf + (size_t)noderow * 64);
      op[lq * 2] = q0;
      op[lq * 2 + 1] = q1;
    }
  }
}

extern "C" void kernel_launch(void* const* d_in, const int* in_sizes, int n_in,
                              void* d_out, int out_size, void* d_ws, size_t ws_size,
                              hipStream_t stream) {
  (void)in_sizes; (void)n_in; (void)out_size; (void)ws_size;
  const float* world_pos = (const float*)d_in[0];
  const float* velocity  = (const float*)d_in[1];
  const int*   eidx      = (const int*)d_in[2];
  const float* eattr     = (const float*)d_in[3];
  const float* youngs    = (const float*)d_in[4];
  const float* onehot    = (const float*)d_in[5];
  const float* tspan     = (const float*)d_in[7];
  const float* ym        = (const float*)d_in[8];
  const float* ys        = (const float*)d_in[9];
  const float* emean     = (const float*)d_in[10];
  const float* estd      = (const float*)d_in[11];
  const float* vmean     = (const float*)d_in[12];
  const float* vstd      = (const float*)d_in[13];
  const float* amean     = (const float*)d_in[14];
  const float* astd      = (const float*)d_in[15];
  const float* w_ne1 = (const float*)d_in[16]; const float* b_ne1 = (const float*)d_in[17];
  const float* w_ne2 = (const float*)d_in[18]; const float* b_ne2 = (const float*)d_in[19];
  const float* w_ee1 = (const float*)d_in[20]; const float* b_ee1 = (const float*)d_in[21];
  const float* w_ee2 = (const float*)d_in[22]; const float* b_ee2 = (const float*)d_in[23];
  const float* w_em1 = (const float*)d_in[24]; const float* b_em1 = (const float*)d_in[25];
  const float* w_em2 = (const float*)d_in[26]; const float* b_em2 = (const float*)d_in[27];
  const float* w_nm1 = (const float*)d_in[28]; const float* b_nm1 = (const float*)d_in[29];
  const float* w_nm2 = (const float*)d_in[30]; const float* b_nm2 = (const float*)d_in[31];
  const float* w_dec1 = (const float*)d_in[32]; const float* b_dec1 = (const float*)d_in[33];
  const float* w_dec2 = (const float*)d_in[34]; const float* b_dec2 = (const float*)d_in[35];

  char* ws = (char*)d_ws;
  float* h_pre  = (float*)ws; ws += (size_t)NN * HD * 4;
  float* hbuf   = (float*)ws; ws += (size_t)NN * HD * 4;
  char* eenc_sw = ws; ws += (size_t)NE * 128;
  unsigned short* emsg_bf = (unsigned short*)ws; ws += (size_t)NE * HD * 2;
  unsigned short* h_bf    = (unsigned short*)ws; ws += (size_t)NN * HD * 2;
  char* w1em  = ws; ws += 64 * 384;
  char* w2em  = ws; ws += 64 * 128;
  char* wnm1s = ws; ws += 64 * 256;
  char* wnm2s = ws; ws += 64 * 128;
  char* wdec1s = ws; ws += 64 * 128;
  char* wne2s = ws; ws += 64 * 128;
  char* wee2s = ws; ws += 64 * 128;
  float* vacc = (float*)ws; ws += (size_t)NN * 3 * 4;
  float* pacc = (float*)ws; ws += (size_t)NN * 3 * 4;
  int* counts  = (int*)ws; ws += (size_t)NN * 4;
  int* fill    = (int*)ws; ws += (size_t)NN * 4;
  int* slot    = (int*)ws; ws += (size_t)NE * 4;
  int* row_ptr = (int*)ws; ws += (size_t)(NN + 1) * 4;
  int* bsums   = (int*)ws; ws += (size_t)128 * 4;

  float* PO = (float*)d_out;
  float* VO = PO + (size_t)TT * NN * 3;

  // --- once-per-launch precompute ---
  k_prep<<<(NN * HD) / 256, 256, 0, stream>>>(world_pos, velocity, PO, VO, counts, fill,
                                              youngs, onehot, ym, ys, w_ne1, b_ne1, h_pre,
                                              w_em1, w_em2, w_nm1, w_nm2, w_dec1, w_ne2, w_ee2,
                                              w1em, w2em, wnm1s, wnm2s, wdec1s, wne2s, wee2s);
  k_edge_enc_mfma<<<NE / 64, 256, 0, stream>>>(eattr, emean, estd, w_ee1, b_ee1, wee2s, b_ee2,
                                               eenc_sw, eidx, counts);
  k_scanA<<<SCAN_NB, 256, 0, stream>>>(counts, row_ptr, bsums);
  k_scanB<<<1, 128, 0, stream>>>(bsums);
  k_scanC<<<SCAN_NB, 256, 0, stream>>>(row_ptr, bsums);
  k_place<<<NE / 256, 256, 0, stream>>>(eidx, row_ptr, fill, slot);

  const int NBLK = (NN + 63) / 64;
  k_enc_mfma<<<NBLK, 256, 0, stream>>>(velocity, vmean, vstd, w_ne1, h_pre, wne2s, b_ne2, hbuf, h_bf);

  for (int s = 0; s < TT - 1; s++) {
    const float* V0 = VO + (size_t)s * NN * 3;
    const float* pos_prev = PO + (size_t)s * NN * 3;
    float* pos_next = PO + (size_t)(s + 1) * NN * 3;
    float* vel_next = VO + (size_t)(s + 1) * NN * 3;
    for (int k = 0; k < 4; k++) {
      k_edge_mfma<<<EDGE_GRID, 256, 0, stream>>>(eidx, slot, h_bf, eenc_sw, w1em, w2em,
                                                 b_em1, b_em2, emsg_bf);
      int do_enc = !(s == TT - 2 && k == 3);
      k_upd_enc<<<NBLK, 256, 0, stream>>>(row_ptr, emsg_bf, hbuf, h_bf,
                                          wnm1s, wnm2s, wdec1s, wne2s,
                                          b_nm1, b_nm2, b_dec1, b_dec2, w_dec2, amean, astd,
                                          w_ne1, h_pre, b_ne2, vmean, vstd,
                                          tspan, s, k, do_enc,
                                          V0, vacc, pacc, pos_prev, pos_next, vel_next);
    }
  }
}

// Round 11
// 393.406 us; speedup vs baseline: 2.0025x; 1.0531x over previous
//
#include <hip/hip_runtime.h>
#include <hip/hip_bf16.h>

#define NN 20000
#define NE 160000
#define HD 64
#define TT 3

typedef unsigned short ushortx8 __attribute__((ext_vector_type(8)));
typedef float f32x4 __attribute__((ext_vector_type(4)));
typedef __bf16 bf16x8 __attribute__((ext_vector_type(8)));

__device__ __forceinline__ unsigned short f2bf(float f) {
  unsigned int x = __float_as_uint(f);
  unsigned int r = (x + 0x7fffu + ((x >> 16) & 1u)) >> 16;  // RNE, finite inputs
  return (unsigned short)r;
}
__device__ __forceinline__ float bf2f(unsigned short u) {
  return __uint_as_float(((unsigned int)u) << 16);
}

// ---------------- fused precompute: init out, zero counts, h_pre(bf16), weight prep ----------------
__global__ __launch_bounds__(256) void k_prep(const float* __restrict__ wp,
    const float* __restrict__ vel, float* __restrict__ PO, float* __restrict__ VO,
    int* __restrict__ counts, int* __restrict__ fill,
    const float* __restrict__ youngs, const float* __restrict__ onehot,
    const float* __restrict__ ym, const float* __restrict__ ys,
    const float* __restrict__ w_ne1, const float* __restrict__ b_ne1,
    unsigned short* __restrict__ h_pre_bf,
    const float* __restrict__ w_em1, const float* __restrict__ w_em2,
    const float* __restrict__ w_nm1, const float* __restrict__ w_nm2,
    const float* __restrict__ w_dec1, const float* __restrict__ w_ne2, const float* __restrict__ w_ee2,
    char* __restrict__ w1em, char* __restrict__ w2em, char* __restrict__ wnm1,
    char* __restrict__ wnm2, char* __restrict__ wdec1, char* __restrict__ wne2,
    char* __restrict__ wee2) {
  int idx = blockIdx.x * 256 + threadIdx.x;
  if (idx < NN * 3) { PO[idx] = wp[idx]; VO[idx] = vel[idx]; }
  if (idx < NN) { counts[idx] = 0; fill[idx] = 0; }
  {  // h_pre (all idx < NN*HD; grid == NN*HD/256)
    int n = idx >> 6, j = idx & 63;
    float a = b_ne1[j];
    float yn = (youngs[n] - ym[0]) / ys[0];
    a += yn * w_ne1[3 * HD + j];
#pragma unroll
    for (int k = 0; k < 9; k++) a += onehot[n * 9 + k] * w_ne1[(4 + k) * HD + j];
    h_pre_bf[idx] = f2bf(a);
  }
  int w = idx;
  if (w < 12288) {
    int j = w / 192, k = w % 192;
    *(unsigned short*)(w1em + j * 384 + ((k * 2) ^ ((j & 7) << 4))) = f2bf(w_em1[k * 64 + j]);
    return;
  }
  w -= 12288;
  if (w < 4096) {
    int j = w >> 6, k = w & 63;
    *(unsigned short*)(w2em + j * 128 + ((k * 2) ^ ((j & 7) << 4))) = f2bf(w_em2[k * 64 + j]);
    return;
  }
  w -= 4096;
  if (w < 8192) {
    int j = w >> 7, k = w & 127;
    *(unsigned short*)(wnm1 + j * 256 + ((k * 2) ^ ((j & 7) << 4))) = f2bf(w_nm1[k * 64 + j]);
    return;
  }
  w -= 8192;
  if (w < 4096) {
    int j = w >> 6, k = w & 63;
    *(unsigned short*)(wnm2 + j * 128 + ((k * 2) ^ ((j & 7) << 4))) = f2bf(w_nm2[k * 64 + j]);
    return;
  }
  w -= 4096;
  if (w < 4096) {
    int j = w >> 6, k = w & 63;
    *(unsigned short*)(wdec1 + j * 128 + ((k * 2) ^ ((j & 7) << 4))) = f2bf(w_dec1[k * 64 + j]);
    return;
  }
  w -= 4096;
  if (w < 4096) {
    int j = w >> 6, k = w & 63;
    *(unsigned short*)(wne2 + j * 128 + ((k * 2) ^ ((j & 7) << 4))) = f2bf(w_ne2[k * 64 + j]);
    return;
  }
  w -= 4096;
  if (w < 4096) {
    int j = w >> 6, k = w & 63;
    *(unsigned short*)(wee2 + j * 128 + ((k * 2) ^ ((j & 7) << 4))) = f2bf(w_ee2[k * 64 + j]);
    return;
  }
}

// ---------------- static edge encoder via MFMA (once) -> pre-swizzled bf16 (+ dst count) ----------------
__global__ __launch_bounds__(256) void k_edge_enc_mfma(const float* __restrict__ eattr,
    const float* __restrict__ emean, const float* __restrict__ estd,
    const float* __restrict__ w_ee1, const float* __restrict__ b_ee1,
    const char* __restrict__ wee2sw, const float* __restrict__ b_ee2,
    char* __restrict__ eenc_sw, const int* __restrict__ eidx, int* __restrict__ counts) {
  __shared__ __align__(16) char s_w2[64 * 128];
  __shared__ __align__(16) char s_hid[64 * 128];
  __shared__ float s_w1[4 * 64], s_b1[64], s_b2[64], s_m[4], s_s[4];
  int tid = threadIdx.x, e0b = blockIdx.x * 64;
  for (int c = tid; c < 512; c += 256) ((ushortx8*)s_w2)[c] = ((const ushortx8*)wee2sw)[c];
  if (tid < 256) s_w1[tid] = w_ee1[tid];
  if (tid < 64) { s_b1[tid] = b_ee1[tid]; s_b2[tid] = b_ee2[tid]; }
  if (tid < 4) { s_m[tid] = emean[tid]; s_s[tid] = estd[tid]; }
  __syncthreads();
  int lane = tid & 63, wv = tid >> 6, l15 = lane & 15, lq = lane >> 4, csub = lq * 8;
  int row_l = wv * 16 + l15, rsw = (l15 & 7) << 4;
  int erow = e0b + row_l;
  if (lq == 0) atomicAdd(&counts[eidx[NE + erow]], 1);  // fused k_count
  float4 at = ((const float4*)eattr)[erow];
  float x0 = (at.x - s_m[0]) / s_s[0];
  float x1 = (at.y - s_m[1]) / s_s[1];
  float x2 = (at.z - s_m[2]) / s_s[2];
  float x3 = (at.w - s_m[3]) / s_s[3];
#pragma unroll 4
  for (int i = 0; i < 16; i++) {
    int rl = wv * 16 + i;
    float y0 = __shfl(x0, i), y1 = __shfl(x1, i), y2 = __shfl(x2, i), y3 = __shfl(x3, i);
    float a = s_b1[lane] + y0 * s_w1[lane] + y1 * s_w1[64 + lane] + y2 * s_w1[128 + lane] + y3 * s_w1[192 + lane];
    *(unsigned short*)(s_hid + rl * 128 + ((lane * 2) ^ ((rl & 7) << 4))) = f2bf(fmaxf(a, 0.f));
  }
  f32x4 acc[4];
#pragma unroll
  for (int n = 0; n < 4; n++) {
    float bv = s_b2[n * 16 + l15];
#pragma unroll
    for (int i = 0; i < 4; i++) acc[n][i] = bv;
  }
#pragma unroll
  for (int kk = 0; kk < 2; kk++) {
    ushortx8 au = *(const ushortx8*)(s_hid + row_l * 128 + (((kk * 32 + csub) * 2) ^ rsw));
    bf16x8 av = __builtin_bit_cast(bf16x8, au);
#pragma unroll
    for (int n = 0; n < 4; n++) {
      int j = n * 16 + l15;
      ushortx8 bu = *(const ushortx8*)(s_w2 + j * 128 + (((kk * 32 + csub) * 2) ^ ((j & 7) << 4)));
      acc[n] = __builtin_amdgcn_mfma_f32_16x16x32_bf16(av, __builtin_bit_cast(bf16x8, bu), acc[n], 0, 0, 0);
    }
  }
#pragma unroll
  for (int n = 0; n < 4; n++) {
#pragma unroll
    for (int i = 0; i < 4; i++) {
      int r = wv * 16 + lq * 4 + i, col = n * 16 + l15;
      *(unsigned short*)(s_hid + r * 128 + ((col * 2) ^ ((r & 7) << 4))) = f2bf(acc[n][i]);
    }
  }
  ushortx8 q0 = *(const ushortx8*)(s_hid + row_l * 128 + lq * 32);
  ushortx8 q1 = *(const ushortx8*)(s_hid + row_l * 128 + lq * 32 + 16);
  *(ushortx8*)(eenc_sw + (size_t)erow * 128 + lq * 32) = q0;
  *(ushortx8*)(eenc_sw + (size_t)erow * 128 + lq * 32 + 16) = q1;
}

// ---------------- CSR build ----------------
#define SCAN_NB ((NN + 255) / 256)
__global__ __launch_bounds__(256) void k_scanA(const int* __restrict__ counts,
    int* __restrict__ row_ptr, int* __restrict__ bsums) {
  __shared__ int tmp[256];
  int tid = threadIdx.x;
  int g = blockIdx.x * 256 + tid;
  int v = (g < NN) ? counts[g] : 0;
  tmp[tid] = v;
  __syncthreads();
#pragma unroll
  for (int off = 1; off < 256; off <<= 1) {
    int t = (tid >= off) ? tmp[tid - off] : 0;
    __syncthreads();
    tmp[tid] += t;
    __syncthreads();
  }
  if (g < NN) row_ptr[g] = tmp[tid] - v;
  if (tid == 255) bsums[blockIdx.x] = tmp[255];
}

__global__ __launch_bounds__(128) void k_scanB(int* __restrict__ bsums) {
  __shared__ int tmp[128];
  int tid = threadIdx.x;
  int v = (tid < SCAN_NB) ? bsums[tid] : 0;
  tmp[tid] = v;
  __syncthreads();
#pragma unroll
  for (int off = 1; off < 128; off <<= 1) {
    int t = (tid >= off) ? tmp[tid - off] : 0;
    __syncthreads();
    tmp[tid] += t;
    __syncthreads();
  }
  if (tid < SCAN_NB) bsums[tid] = tmp[tid] - v;
}

__global__ __launch_bounds__(256) void k_scanC(int* __restrict__ row_ptr, const int* __restrict__ bsums) {
  int g = blockIdx.x * 256 + threadIdx.x;
  if (g < NN) row_ptr[g] += bsums[blockIdx.x];
  if (g == 0) row_ptr[NN] = NE;
}

__global__ __launch_bounds__(256) void k_place(const int* __restrict__ eidx,
    const int* __restrict__ row_ptr, int* __restrict__ fill, int* __restrict__ slot) {
  int e = blockIdx.x * 256 + threadIdx.x;
  if (e >= NE) return;
  int d = eidx[NE + e];
  int f = atomicAdd(&fill[d], 1);
  slot[e] = row_ptr[d] + f;
}

// ---------------- initial node encoder (t=0 only) ----------------
__global__ __launch_bounds__(256) void k_enc_mfma(const float* __restrict__ vel,
    const float* __restrict__ vmean, const float* __restrict__ vstd,
    const float* __restrict__ w_ne1, const unsigned short* __restrict__ h_pre_bf,
    const char* __restrict__ wne2sw, const float* __restrict__ b_ne2,
    unsigned short* __restrict__ h_bf) {
  __shared__ __align__(16) char s_w2[64 * 128];
  __shared__ __align__(16) char s_hid[64 * 128];
  __shared__ float s_w1[3 * 64], s_b2[64], s_vm[3], s_vs[3];
  int tid = threadIdx.x, n0b = blockIdx.x * 64;
  for (int c = tid; c < 512; c += 256) ((ushortx8*)s_w2)[c] = ((const ushortx8*)wne2sw)[c];
  if (tid < 192) s_w1[tid] = w_ne1[tid];
  if (tid < 64) s_b2[tid] = b_ne2[tid];
  if (tid < 3) { s_vm[tid] = vmean[tid]; s_vs[tid] = vstd[tid]; }
  __syncthreads();
  int lane = tid & 63, wv = tid >> 6, l15 = lane & 15, lq = lane >> 4, csub = lq * 8;
#pragma unroll 4
  for (int i = 0; i < 16; i++) {
    int rl = wv * 16 + i, node = n0b + rl;
    float hv = 0.f;
    if (node < NN) {
      float v0 = (vel[node * 3 + 0] - s_vm[0]) / s_vs[0];
      float v1 = (vel[node * 3 + 1] - s_vm[1]) / s_vs[1];
      float v2 = (vel[node * 3 + 2] - s_vm[2]) / s_vs[2];
      float a = bf2f(h_pre_bf[(size_t)node * 64 + lane]) + v0 * s_w1[lane] + v1 * s_w1[64 + lane] + v2 * s_w1[128 + lane];
      hv = fmaxf(a, 0.f);
    }
    *(unsigned short*)(s_hid + rl * 128 + ((lane * 2) ^ ((rl & 7) << 4))) = f2bf(hv);
  }
  int row_l = wv * 16 + l15, rsw = (l15 & 7) << 4;
  f32x4 acc[4];
#pragma unroll
  for (int n = 0; n < 4; n++) {
    float bv = s_b2[n * 16 + l15];
#pragma unroll
    for (int i = 0; i < 4; i++) acc[n][i] = bv;
  }
#pragma unroll
  for (int kk = 0; kk < 2; kk++) {
    ushortx8 au = *(const ushortx8*)(s_hid + row_l * 128 + (((kk * 32 + csub) * 2) ^ rsw));
    bf16x8 av = __builtin_bit_cast(bf16x8, au);
#pragma unroll
    for (int n = 0; n < 4; n++) {
      int j = n * 16 + l15;
      ushortx8 bu = *(const ushortx8*)(s_w2 + j * 128 + (((kk * 32 + csub) * 2) ^ ((j & 7) << 4)));
      acc[n] = __builtin_amdgcn_mfma_f32_16x16x32_bf16(av, __builtin_bit_cast(bf16x8, bu), acc[n], 0, 0, 0);
    }
  }
#pragma unroll
  for (int n = 0; n < 4; n++) {
#pragma unroll
    for (int i = 0; i < 4; i++) {
      int r = wv * 16 + lq * 4 + i, col = n * 16 + l15;
      *(unsigned short*)(s_hid + r * 128 + ((col * 2) ^ ((r & 7) << 4))) = f2bf(acc[n][i]);
    }
  }
  int noderow = n0b + row_l;
  if (noderow < NN) {
    ushortx8 q0 = *(const ushortx8*)(s_hid + row_l * 128 + ((lq * 32) ^ rsw));
    ushortx8 q1 = *(const ushortx8*)(s_hid + row_l * 128 + ((lq * 32 + 16) ^ rsw));
    ushortx8* op = (ushortx8*)(h_bf + (size_t)noderow * 64);
    op[lq * 2] = q0;
    op[lq * 2 + 1] = q1;
  }
}

// ---------------- per-deriv: edge message MLP via MFMA (EXACT R7 structure) ----------------
#define EDGE_GRID 1024
__global__ __launch_bounds__(256, 4) void k_edge_mfma(
    const int* __restrict__ eidx, const int* __restrict__ slot,
    const unsigned short* __restrict__ h_bf, const char* __restrict__ eenc_sw,
    const char* __restrict__ w1sw, const char* __restrict__ w2sw,
    const float* __restrict__ b_em1, const float* __restrict__ b_em2,
    unsigned short* __restrict__ emsg) {
  __shared__ __align__(16) char s_w1[64 * 384];  // 24KB
  __shared__ __align__(16) char s_w2[64 * 128];  // 8KB
  __shared__ __align__(16) char s_eh[64 * 128];  // 8KB: ee tile / hid / out overlay
  int tid = threadIdx.x;
  int lane = tid & 63, wv = tid >> 6, l15 = lane & 15, lq = lane >> 4, csub = lq * 8;
  int erow_loc = wv * 16 + l15;
  int rsw = (l15 & 7) << 4;
  for (int c = tid; c < 1536; c += 256) ((ushortx8*)s_w1)[c] = ((const ushortx8*)w1sw)[c];
  for (int c = tid; c < 512; c += 256) ((ushortx8*)s_w2)[c] = ((const ushortx8*)w2sw)[c];
  float bv1[4], bv2[4];
#pragma unroll
  for (int n = 0; n < 4; n++) { bv1[n] = b_em1[n * 16 + l15]; bv2[n] = b_em2[n * 16 + l15]; }

  const int NT = NE / 64;
  ushortx8 stg0, stg1;
  {
    const ushortx8* src = (const ushortx8*)(eenc_sw + (size_t)blockIdx.x * 64 * 128);
    stg0 = src[tid];
    stg1 = src[tid + 256];
  }
  for (int t = blockIdx.x; t < NT; t += EDGE_GRID) {
    int e0b = t * 64;
    int eg = e0b + erow_loc;
    int sidx = eidx[eg], didx = eidx[NE + eg], sl = slot[eg];
    const ushortx8* hs = (const ushortx8*)(h_bf + (size_t)sidx * HD);
    const ushortx8* hd = (const ushortx8*)(h_bf + (size_t)didx * HD);
    ushortx8 a2 = hs[lq];
    ushortx8 a3 = hs[4 + lq];
    ushortx8 a4 = hd[lq];
    ushortx8 a5 = hd[4 + lq];
    __syncthreads();  // prev tile done with s_eh (1st iter: weights visible)
    ((ushortx8*)s_eh)[tid] = stg0;
    ((ushortx8*)s_eh)[tid + 256] = stg1;
    __syncthreads();  // s_eh ready
    int tn = t + EDGE_GRID;
    if (tn < NT) {  // issue next tile's loads; they complete under the MFMAs below
      const ushortx8* srcn = (const ushortx8*)(eenc_sw + (size_t)tn * 64 * 128);
      stg0 = srcn[tid];
      stg1 = srcn[tid + 256];
    }
    ushortx8 a0 = *(const ushortx8*)(s_eh + erow_loc * 128 + ((csub * 2) ^ rsw));
    ushortx8 a1 = *(const ushortx8*)(s_eh + erow_loc * 128 + ((64 + csub * 2) ^ rsw));
    f32x4 acc[4];
#pragma unroll
    for (int n = 0; n < 4; n++) {
#pragma unroll
      for (int i = 0; i < 4; i++) acc[n][i] = bv1[n];
    }
    ushortx8 af[6] = {a0, a1, a2, a3, a4, a5};
#pragma unroll
    for (int kk = 0; kk < 6; kk++) {
      bf16x8 av = __builtin_bit_cast(bf16x8, af[kk]);
#pragma unroll
      for (int n = 0; n < 4; n++) {
        int j = n * 16 + l15;
        ushortx8 bu = *(const ushortx8*)(s_w1 + j * 384 + (((kk * 32 + csub) * 2) ^ ((j & 7) << 4)));
        acc[n] = __builtin_amdgcn_mfma_f32_16x16x32_bf16(av, __builtin_bit_cast(bf16x8, bu), acc[n], 0, 0, 0);
      }
    }
    // residual C-init from s_eh (ee) BEFORE overwriting with hid (own-wave rows only)
    f32x4 acc2[4];
#pragma unroll
    for (int n = 0; n < 4; n++) {
#pragma unroll
      for (int i = 0; i < 4; i++) {
        int r = wv * 16 + lq * 4 + i, col = n * 16 + l15;
        unsigned short ev = *(const unsigned short*)(s_eh + r * 128 + ((col * 2) ^ ((r & 7) << 4)));
        acc2[n][i] = bv2[n] + bf2f(ev);
      }
    }
    // relu(acc) -> hid into own-wave rows
#pragma unroll
    for (int n = 0; n < 4; n++) {
#pragma unroll
      for (int i = 0; i < 4; i++) {
        int r = wv * 16 + lq * 4 + i, col = n * 16 + l15;
        *(unsigned short*)(s_eh + r * 128 + ((col * 2) ^ ((r & 7) << 4))) = f2bf(fmaxf(acc[n][i], 0.f));
      }
    }
#pragma unroll
    for (int kk = 0; kk < 2; kk++) {
      ushortx8 au = *(const ushortx8*)(s_eh + erow_loc * 128 + (((kk * 32 + csub) * 2) ^ rsw));
      bf16x8 av = __builtin_bit_cast(bf16x8, au);
#pragma unroll
      for (int n = 0; n < 4; n++) {
        int j = n * 16 + l15;
        ushortx8 bu = *(const ushortx8*)(s_w2 + j * 128 + (((kk * 32 + csub) * 2) ^ ((j & 7) << 4)));
        acc2[n] = __builtin_amdgcn_mfma_f32_16x16x32_bf16(av, __builtin_bit_cast(bf16x8, bu), acc2[n], 0, 0, 0);
      }
    }
#pragma unroll
    for (int n = 0; n < 4; n++) {
#pragma unroll
      for (int i = 0; i < 4; i++) {
        int r = wv * 16 + lq * 4 + i, col = n * 16 + l15;
        *(unsigned short*)(s_eh + r * 128 + ((col * 2) ^ ((r & 7) << 4))) = f2bf(acc2[n][i]);
      }
    }
    ushortx8 q0 = *(const ushortx8*)(s_eh + erow_loc * 128 + ((lq * 32) ^ rsw));
    ushortx8 q1 = *(const ushortx8*)(s_eh + erow_loc * 128 + ((lq * 32 + 16) ^ rsw));
    ushortx8* op = (ushortx8*)(emsg + (size_t)sl * HD);
    op[lq * 2] = q0;
    op[lq * 2 + 1] = q1;
  }
}

// ---------------- per-deriv: agg + node MLP + decoder + RK4 accum + NEXT encoder ----------------
// R7 structure; residual from bf16 h_bf (no fp32 hbuf), h_pre in bf16.
__global__ __launch_bounds__(256) void k_upd_enc(
    const int* __restrict__ row_ptr, const unsigned short* __restrict__ emsg,
    unsigned short* __restrict__ h_bf,
    const char* __restrict__ wnm1sw, const char* __restrict__ wnm2sw,
    const char* __restrict__ wdec1sw, const char* __restrict__ wne2sw,
    const float* __restrict__ b_nm1, const float* __restrict__ b_nm2,
    const float* __restrict__ b_dec1, const float* __restrict__ b_dec2,
    const float* __restrict__ w_dec2, const float* __restrict__ amean, const float* __restrict__ astd,
    const float* __restrict__ w_ne1, const unsigned short* __restrict__ h_pre_bf,
    const float* __restrict__ b_ne2, const float* __restrict__ vmean, const float* __restrict__ vstd,
    const float* __restrict__ tspan, int s, int k, int do_enc,
    const float* __restrict__ V0, float* __restrict__ vacc, float* __restrict__ pacc,
    const float* __restrict__ pos_prev, float* __restrict__ pos_next, float* __restrict__ vel_next) {
  __shared__ __align__(16) char s_w1[64 * 256];
  __shared__ __align__(16) char s_w2[64 * 128];
  __shared__ __align__(16) char s_wd1[64 * 128];
  __shared__ __align__(16) char s_w2e[64 * 128];
  __shared__ __align__(16) char s_ah[64 * 128];
  __shared__ float s_b1[64], s_b2[64], s_bd1[64], s_be2[64], s_wd2[192], s_w1e[192];
  __shared__ float s_vm[3], s_vs[3];
  int tid = threadIdx.x, n0b = blockIdx.x * 64;
  for (int c = tid; c < 1024; c += 256) ((ushortx8*)s_w1)[c] = ((const ushortx8*)wnm1sw)[c];
  for (int c = tid; c < 512; c += 256) ((ushortx8*)s_w2)[c] = ((const ushortx8*)wnm2sw)[c];
  for (int c = tid; c < 512; c += 256) ((ushortx8*)s_wd1)[c] = ((const ushortx8*)wdec1sw)[c];
  for (int c = tid; c < 512; c += 256) ((ushortx8*)s_w2e)[c] = ((const ushortx8*)wne2sw)[c];
  if (tid < 64) { s_b1[tid] = b_nm1[tid]; s_b2[tid] = b_nm2[tid]; s_bd1[tid] = b_dec1[tid]; s_be2[tid] = b_ne2[tid]; }
  if (tid < 192) { s_wd2[tid] = w_dec2[tid]; s_w1e[tid] = w_ne1[tid]; }
  if (tid < 3) { s_vm[tid] = vmean[tid]; s_vs[tid] = vstd[tid]; }

  int lane = tid & 63, wv = tid >> 6, l15 = lane & 15, lq = lane >> 4, csub = lq * 8;
  int row_l = wv * 16 + l15, rsw = (l15 & 7) << 4;
  int noderow = n0b + row_l;
  int ncl = noderow < NN ? noderow : NN - 1;
  ushortx8 afh0 = *(const ushortx8*)(h_bf + (size_t)ncl * 64 + csub);
  ushortx8 afh1 = *(const ushortx8*)(h_bf + (size_t)ncl * 64 + 32 + csub);

  // ---- agg: lane = (row in 0..7, ch-group in 0..7), 2 passes, no shuffles ----
  int arow = lane >> 3, ag = lane & 7;
#pragma unroll
  for (int p = 0; p < 2; p++) {
    int rl = wv * 16 + p * 8 + arow, node = n0b + rl;
    float sm[8] = {0.f, 0.f, 0.f, 0.f, 0.f, 0.f, 0.f, 0.f};
    if (node < NN) {
      int b = row_ptr[node], e = row_ptr[node + 1];
      for (int r = b; r < e; r++) {
        ushortx8 u = *(const ushortx8*)(emsg + (size_t)r * HD + ag * 8);
#pragma unroll
        for (int j = 0; j < 8; j++) sm[j] += bf2f(u[j]);
      }
    }
    ushortx8 u;
#pragma unroll
    for (int j = 0; j < 8; j++) u[j] = f2bf(sm[j]);
    *(ushortx8*)(s_ah + rl * 128 + ((ag * 16) ^ ((rl & 7) << 4))) = u;
  }
  __syncthreads();

  // ---- GEMM1: [h | agg] x wnm1 ----
  f32x4 acc[4];
#pragma unroll
  for (int n = 0; n < 4; n++) {
    float bv = s_b1[n * 16 + l15];
#pragma unroll
    for (int i = 0; i < 4; i++) acc[n][i] = bv;
  }
  ushortx8 af[4];
  af[0] = afh0; af[1] = afh1;
  af[2] = *(const ushortx8*)(s_ah + row_l * 128 + ((csub * 2) ^ rsw));
  af[3] = *(const ushortx8*)(s_ah + row_l * 128 + (((32 + csub) * 2) ^ rsw));
#pragma unroll
  for (int kk = 0; kk < 4; kk++) {
    bf16x8 av = __builtin_bit_cast(bf16x8, af[kk]);
#pragma unroll
    for (int n = 0; n < 4; n++) {
      int j = n * 16 + l15;
      ushortx8 bu = *(const ushortx8*)(s_w1 + j * 256 + (((kk * 32 + csub) * 2) ^ ((j & 7) << 4)));
      acc[n] = __builtin_amdgcn_mfma_f32_16x16x32_bf16(av, __builtin_bit_cast(bf16x8, bu), acc[n], 0, 0, 0);
    }
  }
#pragma unroll
  for (int n = 0; n < 4; n++) {
#pragma unroll
    for (int i = 0; i < 4; i++) {
      int r = wv * 16 + lq * 4 + i, col = n * 16 + l15;
      *(unsigned short*)(s_ah + r * 128 + ((col * 2) ^ ((r & 7) << 4))) = f2bf(fmaxf(acc[n][i], 0.f));
    }
  }
  // ---- GEMM2: hu = h(resid bf16) + b2 + hid x wnm2 ----
  f32x4 acc2[4];
#pragma unroll
  for (int n = 0; n < 4; n++) {
#pragma unroll
    for (int i = 0; i < 4; i++) {
      int r = wv * 16 + lq * 4 + i, col = n * 16 + l15;
      int rg = n0b + r; int rgc = rg < NN ? rg : NN - 1;
      acc2[n][i] = s_b2[col] + bf2f(h_bf[(size_t)rgc * 64 + col]);
    }
  }
#pragma unroll
  for (int kk = 0; kk < 2; kk++) {
    ushortx8 au = *(const ushortx8*)(s_ah + row_l * 128 + (((kk * 32 + csub) * 2) ^ rsw));
    bf16x8 av = __builtin_bit_cast(bf16x8, au);
#pragma unroll
    for (int n = 0; n < 4; n++) {
      int j = n * 16 + l15;
      ushortx8 bu = *(const ushortx8*)(s_w2 + j * 128 + (((kk * 32 + csub) * 2) ^ ((j & 7) << 4)));
      acc2[n] = __builtin_amdgcn_mfma_f32_16x16x32_bf16(av, __builtin_bit_cast(bf16x8, bu), acc2[n], 0, 0, 0);
    }
  }
#pragma unroll
  for (int n = 0; n < 4; n++) {
#pragma unroll
    for (int i = 0; i < 4; i++) {
      int r = wv * 16 + lq * 4 + i, col = n * 16 + l15;
      *(unsigned short*)(s_ah + r * 128 + ((col * 2) ^ ((r & 7) << 4))) = f2bf(acc2[n][i]);
    }
  }
  // ---- dec1 ----
  f32x4 acc3[4];
#pragma unroll
  for (int n = 0; n < 4; n++) {
    float bv = s_bd1[n * 16 + l15];
#pragma unroll
    for (int i = 0; i < 4; i++) acc3[n][i] = bv;
  }
#pragma unroll
  for (int kk = 0; kk < 2; kk++) {
    ushortx8 au = *(const ushortx8*)(s_ah + row_l * 128 + (((kk * 32 + csub) * 2) ^ rsw));
    bf16x8 av = __builtin_bit_cast(bf16x8, au);
#pragma unroll
    for (int n = 0; n < 4; n++) {
      int j = n * 16 + l15;
      ushortx8 bu = *(const ushortx8*)(s_wd1 + j * 128 + (((kk * 32 + csub) * 2) ^ ((j & 7) << 4)));
      acc3[n] = __builtin_amdgcn_mfma_f32_16x16x32_bf16(av, __builtin_bit_cast(bf16x8, bu), acc3[n], 0, 0, 0);
    }
  }
#pragma unroll
  for (int n = 0; n < 4; n++) {
#pragma unroll
    for (int i = 0; i < 4; i++) {
      int r = wv * 16 + lq * 4 + i, col = n * 16 + l15;
      *(unsigned short*)(s_ah + r * 128 + ((col * 2) ^ ((r & 7) << 4))) = f2bf(fmaxf(acc3[n][i], 0.f));
    }
  }
  // ---- dec2 ----
  ushortx8 u0 = *(const ushortx8*)(s_ah + row_l * 128 + ((lq * 32) ^ rsw));
  ushortx8 u1 = *(const ushortx8*)(s_ah + row_l * 128 + ((lq * 32 + 16) ^ rsw));
  float p[3] = {0.f, 0.f, 0.f};
#pragma unroll
  for (int i = 0; i < 8; i++) {
    float x0 = bf2f(u0[i]), x1 = bf2f(u1[i]);
    int c0 = lq * 16 + i, c1 = lq * 16 + 8 + i;
#pragma unroll
    for (int t = 0; t < 3; t++) p[t] += x0 * s_wd2[c0 * 3 + t] + x1 * s_wd2[c1 * 3 + t];
  }
#pragma unroll
  for (int t = 0; t < 3; t++) {
    p[t] += __shfl_xor(p[t], 16);
    p[t] += __shfl_xor(p[t], 32);
  }
  // ---- RK4 bookkeeping ----
  float dt = tspan[s + 1] - tspan[s];
  float o[3];
#pragma unroll
  for (int t = 0; t < 3; t++) o[t] = (p[t] + b_dec2[t]) * astd[t] + amean[t];
  const float ck = (k == 2) ? 1.0f : 0.5f;
  float vs[3] = {0.f, 0.f, 0.f};
  if (noderow < NN) {
    if (lq == 0) {
#pragma unroll
      for (int t = 0; t < 3; t++) {
        float v0v = V0[noderow * 3 + t];
        float wk = (k == 0 || k == 3) ? 1.f : 2.f;
        float va = (k == 0) ? o[t] : vacc[noderow * 3 + t] + wk * o[t];
        if (k < 3) {
          vacc[noderow * 3 + t] = va;
          vs[t] = v0v + ck * dt * o[t];
        } else {
          float vn = v0v + (dt / 6.f) * va;
          vel_next[noderow * 3 + t] = vn;
          vs[t] = vn;
        }
      }
    } else if (lq == 1) {
#pragma unroll
      for (int t = 0; t < 3; t++) {
        if (k < 3) {
          float v0v = V0[noderow * 3 + t];
          float vst = v0v + ck * dt * o[t];
          float pa;
          if (k == 0) pa = v0v + 2.f * vst;
          else pa = pacc[noderow * 3 + t] + ((k == 1) ? 2.f : 1.f) * vst;
          pacc[noderow * 3 + t] = pa;
        } else {
          pos_next[noderow * 3 + t] = pos_prev[noderow * 3 + t] + (dt / 6.f) * pacc[noderow * 3 + t];
        }
      }
    }
  }
  // ---- fused encoder for next stage ----
  if (do_enc) {
    for (int i = 0; i < 16; i++) {
      int rl = wv * 16 + i, node = n0b + rl;
      float v0s = __shfl(vs[0], i);
      float v1s = __shfl(vs[1], i);
      float v2s = __shfl(vs[2], i);
      float hv = 0.f;
      if (node < NN) {
        float vn0 = (v0s - s_vm[0]) / s_vs[0];
        float vn1 = (v1s - s_vm[1]) / s_vs[1];
        float vn2 = (v2s - s_vm[2]) / s_vs[2];
        float a = bf2f(h_pre_bf[(size_t)node * 64 + lane]) + vn0 * s_w1e[lane] + vn1 * s_w1e[64 + lane] + vn2 * s_w1e[128 + lane];
        hv = fmaxf(a, 0.f);
      }
      *(unsigned short*)(s_ah + rl * 128 + ((lane * 2) ^ ((rl & 7) << 4))) = f2bf(hv);
    }
    f32x4 ae[4];
#pragma unroll
    for (int n = 0; n < 4; n++) {
      float bv = s_be2[n * 16 + l15];
#pragma unroll
      for (int i = 0; i < 4; i++) ae[n][i] = bv;
    }
#pragma unroll
    for (int kk = 0; kk < 2; kk++) {
      ushortx8 au = *(const ushortx8*)(s_ah + row_l * 128 + (((kk * 32 + csub) * 2) ^ rsw));
      bf16x8 av = __builtin_bit_cast(bf16x8, au);
#pragma unroll
      for (int n = 0; n < 4; n++) {
        int j = n * 16 + l15;
        ushortx8 bu = *(const ushortx8*)(s_w2e + j * 128 + (((kk * 32 + csub) * 2) ^ ((j & 7) << 4)));
        ae[n] = __builtin_amdgcn_mfma_f32_16x16x32_bf16(av, __builtin_bit_cast(bf16x8, bu), ae[n], 0, 0, 0);
      }
    }
    __syncthreads();  // residual reads of h_bf done block-wide before overwrite
#pragma unroll
    for (int n = 0; n < 4; n++) {
#pragma unroll
      for (int i = 0; i < 4; i++) {
        int r = wv * 16 + lq * 4 + i, col = n * 16 + l15;
        *(unsigned short*)(s_ah + r * 128 + ((col * 2) ^ ((r & 7) << 4))) = f2bf(ae[n][i]);
      }
    }
    if (noderow < NN) {
      ushortx8 q0 = *(const ushortx8*)(s_ah + row_l * 128 + ((lq * 32) ^ rsw));
      ushortx8 q1 = *(const ushortx8*)(s_ah + row_l * 128 + ((lq * 32 + 16) ^ rsw));
      ushortx8* op = (ushortx8*)(h_bf + (size_t)noderow * 64);
      op[lq * 2] = q0;
      op[lq * 2 + 1] = q1;
    }
  }
}

extern "C" void kernel_launch(void* const* d_in, const int* in_sizes, int n_in,
                              void* d_out, int out_size, void* d_ws, size_t ws_size,
                              hipStream_t stream) {
  (void)in_sizes; (void)n_in; (void)out_size; (void)ws_size;
  const float* world_pos = (const float*)d_in[0];
  const float* velocity  = (const float*)d_in[1];
  const int*   eidx      = (const int*)d_in[2];
  const float* eattr     = (const float*)d_in[3];
  const float* youngs    = (const float*)d_in[4];
  const float* onehot    = (const float*)d_in[5];
  const float* tspan     = (const float*)d_in[7];
  const float* ym        = (const float*)d_in[8];
  const float* ys        = (const float*)d_in[9];
  const float* emean     = (const float*)d_in[10];
  const float* estd      = (const float*)d_in[11];
  const float* vmean     = (const float*)d_in[12];
  const float* vstd      = (const float*)d_in[13];
  const float* amean     = (const float*)d_in[14];
  const float* astd      = (const float*)d_in[15];
  const float* w_ne1 = (const float*)d_in[16]; const float* b_ne1 = (const float*)d_in[17];
  const float* w_ne2 = (const float*)d_in[18]; const float* b_ne2 = (const float*)d_in[19];
  const float* w_ee1 = (const float*)d_in[20]; const float* b_ee1 = (const float*)d_in[21];
  const float* w_ee2 = (const float*)d_in[22]; const float* b_ee2 = (const float*)d_in[23];
  const float* w_em1 = (const float*)d_in[24]; const float* b_em1 = (const float*)d_in[25];
  const float* w_em2 = (const float*)d_in[26]; const float* b_em2 = (const float*)d_in[27];
  const float* w_nm1 = (const float*)d_in[28]; const float* b_nm1 = (const float*)d_in[29];
  const float* w_nm2 = (const float*)d_in[30]; const float* b_nm2 = (const float*)d_in[31];
  const float* w_dec1 = (const float*)d_in[32]; const float* b_dec1 = (const float*)d_in[33];
  const float* w_dec2 = (const float*)d_in[34]; const float* b_dec2 = (const float*)d_in[35];

  char* ws = (char*)d_ws;
  unsigned short* h_pre_bf = (unsigned short*)ws; ws += (size_t)NN * HD * 2;
  char* eenc_sw = ws; ws += (size_t)NE * 128;
  unsigned short* emsg_bf = (unsigned short*)ws; ws += (size_t)NE * HD * 2;
  unsigned short* h_bf    = (unsigned short*)ws; ws += (size_t)NN * HD * 2;
  char* w1em  = ws; ws += 64 * 384;
  char* w2em  = ws; ws += 64 * 128;
  char* wnm1s = ws; ws += 64 * 256;
  char* wnm2s = ws; ws += 64 * 128;
  char* wdec1s = ws; ws += 64 * 128;
  char* wne2s = ws; ws += 64 * 128;
  char* wee2s = ws; ws += 64 * 128;
  float* vacc = (float*)ws; ws += (size_t)NN * 3 * 4;
  float* pacc = (float*)ws; ws += (size_t)NN * 3 * 4;
  int* counts  = (int*)ws; ws += (size_t)NN * 4;
  int* fill    = (int*)ws; ws += (size_t)NN * 4;
  int* slot    = (int*)ws; ws += (size_t)NE * 4;
  int* row_ptr = (int*)ws; ws += (size_t)(NN + 1) * 4;
  int* bsums   = (int*)ws; ws += (size_t)128 * 4;

  float* PO = (float*)d_out;
  float* VO = PO + (size_t)TT * NN * 3;

  // --- once-per-launch precompute ---
  k_prep<<<(NN * HD) / 256, 256, 0, stream>>>(world_pos, velocity, PO, VO, counts, fill,
                                              youngs, onehot, ym, ys, w_ne1, b_ne1, h_pre_bf,
                                              w_em1, w_em2, w_nm1, w_nm2, w_dec1, w_ne2, w_ee2,
                                              w1em, w2em, wnm1s, wnm2s, wdec1s, wne2s, wee2s);
  k_edge_enc_mfma<<<NE / 64, 256, 0, stream>>>(eattr, emean, estd, w_ee1, b_ee1, wee2s, b_ee2,
                                               eenc_sw, eidx, counts);
  k_scanA<<<SCAN_NB, 256, 0, stream>>>(counts, row_ptr, bsums);
  k_scanB<<<1, 128, 0, stream>>>(bsums);
  k_scanC<<<SCAN_NB, 256, 0, stream>>>(row_ptr, bsums);
  k_place<<<NE / 256, 256, 0, stream>>>(eidx, row_ptr, fill, slot);

  const int NBLK = (NN + 63) / 64;
  k_enc_mfma<<<NBLK, 256, 0, stream>>>(velocity, vmean, vstd, w_ne1, h_pre_bf, wne2s, b_ne2, h_bf);

  for (int s = 0; s < TT - 1; s++) {
    const float* V0 = VO + (size_t)s * NN * 3;
    const float* pos_prev = PO + (size_t)s * NN * 3;
    float* pos_next = PO + (size_t)(s + 1) * NN * 3;
    float* vel_next = VO + (size_t)(s + 1) * NN * 3;
    for (int k = 0; k < 4; k++) {
      k_edge_mfma<<<EDGE_GRID, 256, 0, stream>>>(eidx, slot, h_bf, eenc_sw, w1em, w2em,
                                                 b_em1, b_em2, emsg_bf);
      int do_enc = !(s == TT - 2 && k == 3);
      k_upd_enc<<<NBLK, 256, 0, stream>>>(row_ptr, emsg_bf, h_bf,
                                          wnm1s, wnm2s, wdec1s, wne2s,
                                          b_nm1, b_nm2, b_dec1, b_dec2, w_dec2, amean, astd,
                                          w_ne1, h_pre_bf, b_ne2, vmean, vstd,
                                          tspan, s, k, do_enc,
                                          V0, vacc, pacc, pos_prev, pos_next, vel_next);
    }
  }
}